// Round 1
// baseline (402.536 us; speedup 1.0000x reference)
//
#include <hip/hip_runtime.h>
#include <math.h>

#define N_NODES 10000
#define N_EDGES 320000
#define IN_F 256
#define OUT_F 256
#define SLOPE 0.2f
#define MAXK 1024

// ---------------------------------------------------------------------------
// K1: Wh = features @ W + b_lin ; also atomically accumulate column sum S.
// One block = 16 nodes, 256 threads (thread = output feature).
// ---------------------------------------------------------------------------
__global__ void wh_kernel(const float* __restrict__ feat, const float* __restrict__ W,
                          const float* __restrict__ b, float* __restrict__ Wh,
                          float* __restrict__ S) {
    __shared__ float sf[16][IN_F];
    const int nb  = blockIdx.x * 16;
    const int tid = threadIdx.x;
    for (int i = tid; i < 16 * IN_F; i += 256)
        sf[i / IN_F][i % IN_F] = feat[nb * IN_F + i];
    __syncthreads();
    float acc[16];
    const float bf = b[tid];
#pragma unroll
    for (int r = 0; r < 16; ++r) acc[r] = bf;
    for (int k = 0; k < IN_F; ++k) {
        const float w = W[k * OUT_F + tid];   // coalesced; W stays in L2
#pragma unroll
        for (int r = 0; r < 16; ++r) acc[r] = fmaf(sf[r][k], w, acc[r]);
    }
    float colsum = 0.f;
#pragma unroll
    for (int r = 0; r < 16; ++r) {
        Wh[(nb + r) * OUT_F + tid] = acc[r];
        colsum += acc[r];
    }
    atomicAdd(&S[tid], colsum);               // 625 atomics per feature — cheap
}

// ---------------------------------------------------------------------------
// K2: per-node projections ds[n] = Wh[n]·Wa_src, dd[n] = Wh[n]·Wa_dst.
// One wave (64 lanes) per node; float4 loads cover the 256-wide row.
// ---------------------------------------------------------------------------
__global__ void proj_kernel(const float* __restrict__ Wh, const float* __restrict__ Was,
                            const float* __restrict__ Wad, float* __restrict__ ds,
                            float* __restrict__ dd) {
    const int node = (blockIdx.x * blockDim.x + threadIdx.x) >> 6;
    const int lane = threadIdx.x & 63;
    if (node >= N_NODES) return;
    const float4 a  = ((const float4*)(Wh + node * OUT_F))[lane];
    const float4 ws = ((const float4*)Was)[lane];
    const float4 wd = ((const float4*)Wad)[lane];
    float s = a.x * ws.x + a.y * ws.y + a.z * ws.z + a.w * ws.w;
    float d = a.x * wd.x + a.y * wd.y + a.z * wd.z + a.w * wd.w;
    for (int m = 32; m; m >>= 1) { s += __shfl_xor(s, m); d += __shfl_xor(d, m); }
    if (lane == 0) { ds[node] = s; dd[node] = d; }
}

// ---------------------------------------------------------------------------
// K3: per-edge logit e[i] = ds[u] + dd[v] + b_att, plus per-row touch counting
// (each edge touches row u and row v).
// ---------------------------------------------------------------------------
__global__ void e_cnt_kernel(const int* __restrict__ eu, const int* __restrict__ ev,
                             const float* __restrict__ ds, const float* __restrict__ dd,
                             const float* __restrict__ batt, float* __restrict__ e,
                             int* __restrict__ cnt) {
    const int i = blockIdx.x * blockDim.x + threadIdx.x;
    if (i >= N_EDGES) return;
    const int u = eu[i], v = ev[i];
    e[i] = ds[u] + dd[v] + batt[0];
    atomicAdd(&cnt[u], 1);
    atomicAdd(&cnt[v], 1);
}

// ---------------------------------------------------------------------------
// K4: exclusive prefix-sum of cnt[] -> offs[] (and cursor[] copy).
// Single 1024-thread block; wave-shuffle scan, 10 chunks.
// ---------------------------------------------------------------------------
__global__ void scan_kernel(const int* __restrict__ cnt, int* __restrict__ offs,
                            int* __restrict__ cursor) {
    __shared__ int wsum[16];
    __shared__ int s_running;
    const int tid  = threadIdx.x;
    const int lane = tid & 63, wave = tid >> 6;
    if (tid == 0) s_running = 0;
    __syncthreads();
    for (int base = 0; base < N_NODES; base += 1024) {
        const int i = base + tid;
        const int x = (i < N_NODES) ? cnt[i] : 0;
        int s = x;
        for (int d = 1; d < 64; d <<= 1) {
            const int t = __shfl_up(s, d);
            if (lane >= d) s += t;
        }
        if (lane == 63) wsum[wave] = s;
        __syncthreads();
        if (wave == 0 && lane < 16) {
            int wsv = wsum[lane];
            for (int d = 1; d < 16; d <<= 1) {
                const int t = __shfl_up(wsv, d);
                if (lane >= d) wsv += t;
            }
            wsum[lane] = wsv;                 // inclusive scan of wave sums
        }
        __syncthreads();
        const int wave_excl = (wave == 0) ? 0 : wsum[wave - 1];
        const int excl = s - x + wave_excl + s_running;
        if (i < N_NODES) { offs[i] = excl; cursor[i] = excl; }
        __syncthreads();
        if (tid == 1023) s_running += wsum[15];
        __syncthreads();
    }
    if (tid == 0) offs[N_NODES] = s_running;
}

// ---------------------------------------------------------------------------
// K5: scatter touches into CSR. order encodes jnp scatter sequence:
// phase1 (u,v) has order i, phase2 (v,u) has order N_EDGES+i — last wins.
// ---------------------------------------------------------------------------
__global__ void scatter_kernel(const int* __restrict__ eu, const int* __restrict__ ev,
                               const float* __restrict__ e, int* __restrict__ cursor,
                               int* __restrict__ tcol, int* __restrict__ tord,
                               float* __restrict__ tval) {
    const int i = blockIdx.x * blockDim.x + threadIdx.x;
    if (i >= N_EDGES) return;
    const int u = eu[i], v = ev[i];
    const float ei = e[i];
    const int p = atomicAdd(&cursor[u], 1);
    tcol[p] = v; tord[p] = i;           tval[p] = ei;
    const int q = atomicAdd(&cursor[v], 1);
    tcol[q] = u; tord[q] = N_EDGES + i; tval[q] = ei;
}

// ---------------------------------------------------------------------------
// K6: per-row dedupe + softmax-weighted accumulate + ELU.
// One block (256 threads) per row; thread = output feature.
// out[r] = elu( (S + Σ w_j·Wh[c_j]) / (N + Σ w_j) ), w = exp(lrelu(e)) - 1,
// summed over cells whose LAST touch this is (max order per (row,col)).
// ---------------------------------------------------------------------------
__global__ void row_kernel(const float* __restrict__ Wh, const float* __restrict__ S,
                           const int* __restrict__ offs, const int* __restrict__ cnt,
                           const int* __restrict__ tcol, const int* __restrict__ tord,
                           const float* __restrict__ tval, float* __restrict__ out) {
    __shared__ int   scol[MAXK];
    __shared__ int   sord[MAXK];
    __shared__ float sw[MAXK];
    const int r   = blockIdx.x;
    const int tid = threadIdx.x;
    const int base = offs[r];
    int k = cnt[r];
    if (k > MAXK) k = MAXK;               // impossible for this input; OOB guard
    for (int j = tid; j < k; j += 256) {
        scol[j] = tcol[base + j];
        sord[j] = tord[base + j];
        const float x = tval[base + j];
        const float l = x >= 0.f ? x : SLOPE * x;
        sw[j] = __expf(l) - 1.f;
    }
    __syncthreads();
    // dedupe: zero every touch that is not the max-order touch of its column
    for (int j = tid; j < k; j += 256) {
        const int c = scol[j], o = sord[j];
        for (int t = 0; t < k; ++t) {
            if (scol[t] == c && sord[t] > o) { sw[j] = 0.f; break; }
        }
    }
    __syncthreads();
    float acc  = S[tid];
    float wsum = 0.f;
    for (int j = 0; j < k; ++j) {
        const float w = sw[j];            // LDS broadcast, uniform across block
        wsum += w;
        if (w != 0.f) acc += w * Wh[scol[j] * OUT_F + tid];  // coalesced gather
    }
    const float x = acc / ((float)N_NODES + wsum);
    out[r * OUT_F + tid] = x > 0.f ? x : expm1f(x);
}

// ---------------------------------------------------------------------------
extern "C" void kernel_launch(void* const* d_in, const int* in_sizes, int n_in,
                              void* d_out, int out_size, void* d_ws, size_t ws_size,
                              hipStream_t stream) {
    const float* feat = (const float*)d_in[0];
    const int*   eu   = (const int*)d_in[1];
    const int*   ev   = (const int*)d_in[2];
    const float* W    = (const float*)d_in[3];
    const float* blin = (const float*)d_in[4];
    const float* Was  = (const float*)d_in[5];
    const float* Wad  = (const float*)d_in[6];
    const float* batt = (const float*)d_in[7];
    float* out = (float*)d_out;

    float* ws    = (float*)d_ws;
    float* Wh    = ws;            ws += (size_t)N_NODES * OUT_F;   // 10.24 MB
    float* S     = ws;            ws += OUT_F;
    float* dsv   = ws;            ws += N_NODES;
    float* ddv   = ws;            ws += N_NODES;
    float* e     = ws;            ws += N_EDGES;
    int*   cnt   = (int*)ws;      ws += N_NODES;
    int*   offs  = (int*)ws;      ws += N_NODES + 1;
    int*   curs  = (int*)ws;      ws += N_NODES;
    int*   tcol  = (int*)ws;      ws += 2 * N_EDGES;
    int*   tord  = (int*)ws;      ws += 2 * N_EDGES;
    float* tval  = ws;            ws += 2 * N_EDGES;                // total ~19.4 MB

    hipMemsetAsync(S,   0, OUT_F   * sizeof(float), stream);
    hipMemsetAsync(cnt, 0, N_NODES * sizeof(int),   stream);

    wh_kernel   <<<N_NODES / 16,              256,  0, stream>>>(feat, W, blin, Wh, S);
    proj_kernel <<<(N_NODES * 64 + 255) / 256, 256, 0, stream>>>(Wh, Was, Wad, dsv, ddv);
    e_cnt_kernel<<<(N_EDGES + 255) / 256,     256,  0, stream>>>(eu, ev, dsv, ddv, batt, e, cnt);
    scan_kernel <<<1,                         1024, 0, stream>>>(cnt, offs, curs);
    scatter_kernel<<<(N_EDGES + 255) / 256,   256,  0, stream>>>(eu, ev, e, curs, tcol, tord, tval);
    row_kernel  <<<N_NODES,                   256,  0, stream>>>(Wh, S, offs, cnt, tcol, tord, tval, out);
}

// Round 2
// 299.935 us; speedup vs baseline: 1.3421x; 1.3421x over previous
//
#include <hip/hip_runtime.h>
#include <math.h>

#define N_NODES 10000
#define N_EDGES 320000
#define IN_F 256
#define OUT_F 256
#define SLOPE 0.2f
#define MAXK 1024

__device__ __forceinline__ unsigned short f2bf_rtn(float x) {
    unsigned int u = __float_as_uint(x);
    u = (u + 0x7FFFu + ((u >> 16) & 1u)) >> 16;
    return (unsigned short)u;
}

// ---------------------------------------------------------------------------
// K1: fused Wh GEMM + bf16 copy + per-node projections (ds,dd) + column sum S.
// Block = 16 rows x 256 cols, 256 threads. Wave rg owns rows rg*4..rg*4+3
// (wave-uniform -> sf reads are LDS broadcasts). Thread = 4 rows x 4 cols.
// W staged in LDS per 32-k chunk (kills redundant global W re-reads).
// ---------------------------------------------------------------------------
__global__ __launch_bounds__(256) void wh_kernel(
    const float* __restrict__ feat, const float* __restrict__ W,
    const float* __restrict__ b, const float* __restrict__ Was,
    const float* __restrict__ Wad, unsigned short* __restrict__ WhB,
    float* __restrict__ ds, float* __restrict__ dd, float* __restrict__ S)
{
    __shared__ float sf[16][IN_F];        // 16 KB feature tile
    __shared__ float sWl[32 * OUT_F];     // 32 KB W k-chunk
    __shared__ float psum[4][OUT_F];      // 4 KB column-sum partials
    const int nb  = blockIdx.x * 16;
    const int tid = threadIdx.x;
    const int rg  = tid >> 6;             // wave id 0..3 -> row group
    const int cg  = tid & 63;             // lane -> col group (4 cols)

    {   // stage features (coalesced float4)
        const float4* src = (const float4*)(feat + (size_t)nb * IN_F);
        float4* dst = (float4*)sf;
        for (int i = tid; i < 16 * IN_F / 4; i += 256) dst[i] = src[i];
    }

    float4 acc[4];
    const float4 bias = ((const float4*)b)[cg];
#pragma unroll
    for (int i = 0; i < 4; ++i) acc[i] = bias;

    for (int kc = 0; kc < IN_F; kc += 32) {
        __syncthreads();                  // protect sWl (and first-iter sf)
        {   // stage W[kc..kc+32][0..256): 2048 float4
            const float4* wsrc = (const float4*)(W + (size_t)kc * OUT_F);
            float4* wdst = (float4*)sWl;
            for (int i = tid; i < 32 * OUT_F / 4; i += 256) wdst[i] = wsrc[i];
        }
        __syncthreads();
#pragma unroll
        for (int kk = 0; kk < 32; kk += 4) {
            const float4 w0 = *(const float4*)&sWl[(kk + 0) * OUT_F + cg * 4];
            const float4 w1 = *(const float4*)&sWl[(kk + 1) * OUT_F + cg * 4];
            const float4 w2 = *(const float4*)&sWl[(kk + 2) * OUT_F + cg * 4];
            const float4 w3 = *(const float4*)&sWl[(kk + 3) * OUT_F + cg * 4];
#pragma unroll
            for (int i = 0; i < 4; ++i) {
                const float4 f = *(const float4*)&sf[rg * 4 + i][kc + kk]; // broadcast
                acc[i].x = fmaf(f.x, w0.x, acc[i].x);
                acc[i].y = fmaf(f.x, w0.y, acc[i].y);
                acc[i].z = fmaf(f.x, w0.z, acc[i].z);
                acc[i].w = fmaf(f.x, w0.w, acc[i].w);
                acc[i].x = fmaf(f.y, w1.x, acc[i].x);
                acc[i].y = fmaf(f.y, w1.y, acc[i].y);
                acc[i].z = fmaf(f.y, w1.z, acc[i].z);
                acc[i].w = fmaf(f.y, w1.w, acc[i].w);
                acc[i].x = fmaf(f.z, w2.x, acc[i].x);
                acc[i].y = fmaf(f.z, w2.y, acc[i].y);
                acc[i].z = fmaf(f.z, w2.z, acc[i].z);
                acc[i].w = fmaf(f.z, w2.w, acc[i].w);
                acc[i].x = fmaf(f.w, w3.x, acc[i].x);
                acc[i].y = fmaf(f.w, w3.y, acc[i].y);
                acc[i].z = fmaf(f.w, w3.z, acc[i].z);
                acc[i].w = fmaf(f.w, w3.w, acc[i].w);
            }
        }
    }

    // bf16 Wh for the gather path (RTN)
#pragma unroll
    for (int i = 0; i < 4; ++i) {
        const int row = nb + rg * 4 + i;
        ushort4 p;
        p.x = f2bf_rtn(acc[i].x); p.y = f2bf_rtn(acc[i].y);
        p.z = f2bf_rtn(acc[i].z); p.w = f2bf_rtn(acc[i].w);
        ((ushort4*)(WhB + (size_t)row * OUT_F))[cg] = p;
    }

    // ds/dd: in-register dot + full-wave shuffle reduce (rows wave-uniform)
    const float4 was4 = ((const float4*)Was)[cg];
    const float4 wad4 = ((const float4*)Wad)[cg];
#pragma unroll
    for (int i = 0; i < 4; ++i) {
        float s = acc[i].x * was4.x + acc[i].y * was4.y + acc[i].z * was4.z + acc[i].w * was4.w;
        float d = acc[i].x * wad4.x + acc[i].y * wad4.y + acc[i].z * wad4.z + acc[i].w * wad4.w;
        for (int m = 32; m; m >>= 1) { s += __shfl_xor(s, m); d += __shfl_xor(d, m); }
        if (cg == 0) { const int row = nb + rg * 4 + i; ds[row] = s; dd[row] = d; }
    }

    // column sums -> S (one atomic per col per block)
    float4 cp;
    cp.x = acc[0].x + acc[1].x + acc[2].x + acc[3].x;
    cp.y = acc[0].y + acc[1].y + acc[2].y + acc[3].y;
    cp.z = acc[0].z + acc[1].z + acc[2].z + acc[3].z;
    cp.w = acc[0].w + acc[1].w + acc[2].w + acc[3].w;
    *(float4*)&psum[rg][cg * 4] = cp;
    __syncthreads();
    atomicAdd(&S[tid], psum[0][tid] + psum[1][tid] + psum[2][tid] + psum[3][tid]);
}

// ---------------------------------------------------------------------------
// K2: per-edge logit + per-row touch counts.
// ---------------------------------------------------------------------------
__global__ void e_cnt_kernel(const int* __restrict__ eu, const int* __restrict__ ev,
                             const float* __restrict__ ds, const float* __restrict__ dd,
                             const float* __restrict__ batt, float* __restrict__ e,
                             int* __restrict__ cnt) {
    const int i = blockIdx.x * blockDim.x + threadIdx.x;
    if (i >= N_EDGES) return;
    const int u = eu[i], v = ev[i];
    e[i] = ds[u] + dd[v] + batt[0];
    atomicAdd(&cnt[u], 1);
    atomicAdd(&cnt[v], 1);
}

// ---------------------------------------------------------------------------
// K3: exclusive prefix-sum of cnt[] -> offs[], cursor[].
// ---------------------------------------------------------------------------
__global__ void scan_kernel(const int* __restrict__ cnt, int* __restrict__ offs,
                            int* __restrict__ cursor) {
    __shared__ int wsum[16];
    __shared__ int s_running;
    const int tid  = threadIdx.x;
    const int lane = tid & 63, wave = tid >> 6;
    if (tid == 0) s_running = 0;
    __syncthreads();
    for (int base = 0; base < N_NODES; base += 1024) {
        const int i = base + tid;
        const int x = (i < N_NODES) ? cnt[i] : 0;
        int s = x;
        for (int d = 1; d < 64; d <<= 1) {
            const int t = __shfl_up(s, d);
            if (lane >= d) s += t;
        }
        if (lane == 63) wsum[wave] = s;
        __syncthreads();
        if (wave == 0 && lane < 16) {
            int wsv = wsum[lane];
            for (int d = 1; d < 16; d <<= 1) {
                const int t = __shfl_up(wsv, d);
                if (lane >= d) wsv += t;
            }
            wsum[lane] = wsv;
        }
        __syncthreads();
        const int wave_excl = (wave == 0) ? 0 : wsum[wave - 1];
        const int excl = s - x + wave_excl + s_running;
        if (i < N_NODES) { offs[i] = excl; cursor[i] = excl; }
        __syncthreads();
        if (tid == 1023) s_running += wsum[15];
        __syncthreads();
    }
    if (tid == 0) offs[N_NODES] = s_running;
}

// ---------------------------------------------------------------------------
// K4: scatter touches into CSR as one int4 (col, ord, val, pad) per touch.
// ---------------------------------------------------------------------------
__global__ void scatter_kernel(const int* __restrict__ eu, const int* __restrict__ ev,
                               const float* __restrict__ e, int* __restrict__ cursor,
                               int4* __restrict__ touch) {
    const int i = blockIdx.x * blockDim.x + threadIdx.x;
    if (i >= N_EDGES) return;
    const int u = eu[i], v = ev[i];
    const int ei = __float_as_int(e[i]);
    int4 a; a.x = v; a.y = i;           a.z = ei; a.w = 0;
    touch[atomicAdd(&cursor[u], 1)] = a;
    int4 c; c.x = u; c.y = N_EDGES + i; c.z = ei; c.w = 0;
    touch[atomicAdd(&cursor[v], 1)] = c;
}

// ---------------------------------------------------------------------------
// K5: per-row dedupe + softmax-weighted accumulate + ELU.
// out[r] = elu((S + sum w_j*Wh[c_j]) / (N + sum w_j)), w = exp(lrelu(e)) - 1.
// 4x unrolled, branch-free gather from bf16 Wh, 4 independent acc chains.
// ---------------------------------------------------------------------------
__global__ __launch_bounds__(256) void row_kernel(
    const unsigned short* __restrict__ WhB, const float* __restrict__ S,
    const int* __restrict__ offs, const int* __restrict__ cnt,
    const int4* __restrict__ touch, float* __restrict__ out)
{
    __shared__ float sw[MAXK];
    __shared__ int   scol[MAXK];
    __shared__ int   sord[MAXK];
    const int r = blockIdx.x;
    const int tid = threadIdx.x;
    const int base = offs[r];
    int k = cnt[r];
    if (k > MAXK - 4) k = MAXK - 4;       // OOB guard (k ~ Poisson(64) here)
    const int k4 = (k + 3) & ~3;
    for (int j = tid; j < k4; j += 256) {
        if (j < k) {
            const int4 t = touch[base + j];
            scol[j] = t.x; sord[j] = t.y;
            const float x = __int_as_float(t.z);
            const float l = x >= 0.f ? x : SLOPE * x;
            sw[j] = __expf(l) - 1.f;
        } else { scol[j] = 0; sord[j] = 0; sw[j] = 0.f; }  // pad: w=0 is inert
    }
    __syncthreads();
    // dedupe: zero every touch that is not the last (max-order) of its column
    for (int j = tid; j < k; j += 256) {
        const int c = scol[j], o = sord[j];
        for (int t = 0; t < k; ++t)
            if (scol[t] == c && sord[t] > o) { sw[j] = 0.f; break; }
    }
    __syncthreads();

    float acc0 = S[tid], acc1 = 0.f, acc2 = 0.f, acc3 = 0.f;
    float s0 = 0.f, s1 = 0.f, s2 = 0.f, s3 = 0.f;
    const unsigned short* wb = WhB + tid;
    for (int j = 0; j < k4; j += 4) {
        const float4 w4 = *(const float4*)&sw[j];    // LDS b128 broadcast
        const int4   c4 = *(const int4*)&scol[j];    // LDS b128 broadcast
        const float x0 = __uint_as_float((unsigned)wb[(size_t)c4.x * OUT_F] << 16);
        const float x1 = __uint_as_float((unsigned)wb[(size_t)c4.y * OUT_F] << 16);
        const float x2 = __uint_as_float((unsigned)wb[(size_t)c4.z * OUT_F] << 16);
        const float x3 = __uint_as_float((unsigned)wb[(size_t)c4.w * OUT_F] << 16);
        acc0 = fmaf(w4.x, x0, acc0); s0 += w4.x;
        acc1 = fmaf(w4.y, x1, acc1); s1 += w4.y;
        acc2 = fmaf(w4.z, x2, acc2); s2 += w4.z;
        acc3 = fmaf(w4.w, x3, acc3); s3 += w4.w;
    }
    const float wsum = (s0 + s1) + (s2 + s3);
    const float a = ((acc0 + acc1) + (acc2 + acc3)) / ((float)N_NODES + wsum);
    out[(size_t)r * OUT_F + tid] = a > 0.f ? a : expm1f(a);
}

// ---------------------------------------------------------------------------
extern "C" void kernel_launch(void* const* d_in, const int* in_sizes, int n_in,
                              void* d_out, int out_size, void* d_ws, size_t ws_size,
                              hipStream_t stream) {
    const float* feat = (const float*)d_in[0];
    const int*   eu   = (const int*)d_in[1];
    const int*   ev   = (const int*)d_in[2];
    const float* W    = (const float*)d_in[3];
    const float* blin = (const float*)d_in[4];
    const float* Was  = (const float*)d_in[5];
    const float* Wad  = (const float*)d_in[6];
    const float* batt = (const float*)d_in[7];
    float* out = (float*)d_out;

    // workspace layout (16B-aligned slices)
    char* p = (char*)d_ws;
    int4* touch = (int4*)p;                 p += (size_t)2 * N_EDGES * 16;   // 10.24 MB
    unsigned short* WhB = (unsigned short*)p; p += (size_t)N_NODES * OUT_F * 2; // 5.12 MB
    float* S    = (float*)p;                p += OUT_F * 4;
    float* dsv  = (float*)p;                p += N_NODES * 4;
    float* ddv  = (float*)p;                p += N_NODES * 4;
    float* e    = (float*)p;                p += N_EDGES * 4;
    int*   cnt  = (int*)p;                  p += N_NODES * 4;
    int*   offs = (int*)p;                  p += (N_NODES + 1) * 4;
    int*   curs = (int*)p;                  p += N_NODES * 4;

    hipMemsetAsync(S,   0, OUT_F   * sizeof(float), stream);
    hipMemsetAsync(cnt, 0, N_NODES * sizeof(int),   stream);

    wh_kernel     <<<N_NODES / 16,          256,  0, stream>>>(feat, W, blin, Was, Wad, WhB, dsv, ddv, S);
    e_cnt_kernel  <<<(N_EDGES + 255) / 256, 256,  0, stream>>>(eu, ev, dsv, ddv, batt, e, cnt);
    scan_kernel   <<<1,                     1024, 0, stream>>>(cnt, offs, curs);
    scatter_kernel<<<(N_EDGES + 255) / 256, 256,  0, stream>>>(eu, ev, e, curs, touch);
    row_kernel    <<<N_NODES,               256,  0, stream>>>(WhB, S, offs, cnt, touch, out);
}

// Round 3
// 280.742 us; speedup vs baseline: 1.4338x; 1.0684x over previous
//
#include <hip/hip_runtime.h>
#include <math.h>

#define N_NODES 10000
#define N_EDGES 320000
#define IN_F 256
#define OUT_F 256
#define SLOPE 0.2f
#define CAP 128   // per-row touch capacity; degree ~ Poisson(64), P(>128) ~ 1e-11/node

__device__ __forceinline__ unsigned short f2bf_rtn(float x) {
    unsigned int u = __float_as_uint(x);
    u = (u + 0x7FFFu + ((u >> 16) & 1u)) >> 16;
    return (unsigned short)u;
}

// ---------------------------------------------------------------------------
// K1: fused Wh GEMM + bf16 split-plane copy + projections (ds,dd) + colsum S.
// Block = 16 rows x 256 cols, 256 threads. Wave rg owns rows rg*4..rg*4+3
// (wave-uniform -> sf reads are LDS broadcasts). Thread = 4 rows x 4 cols.
// WhB layout: plane h (features h*128..h*128+127) = WhB[(h*N + node)*128 + f],
// so each 2.56 MB plane fits a per-XCD 4 MiB L2 for the row-kernel gather.
// ---------------------------------------------------------------------------
__global__ __launch_bounds__(256) void wh_kernel(
    const float* __restrict__ feat, const float* __restrict__ W,
    const float* __restrict__ b, const float* __restrict__ Was,
    const float* __restrict__ Wad, unsigned short* __restrict__ WhB,
    float* __restrict__ ds, float* __restrict__ dd, float* __restrict__ S)
{
    __shared__ float sf[16][IN_F];        // 16 KB feature tile
    __shared__ float sWl[32 * OUT_F];     // 32 KB W k-chunk
    __shared__ float psum[4][OUT_F];      // 4 KB column-sum partials
    const int nb  = blockIdx.x * 16;
    const int tid = threadIdx.x;
    const int rg  = tid >> 6;             // wave id 0..3 -> row group
    const int cg  = tid & 63;             // lane -> col group (4 cols)

    {   // stage features (coalesced float4)
        const float4* src = (const float4*)(feat + (size_t)nb * IN_F);
        float4* dst = (float4*)sf;
        for (int i = tid; i < 16 * IN_F / 4; i += 256) dst[i] = src[i];
    }

    float4 acc[4];
    const float4 bias = ((const float4*)b)[cg];
#pragma unroll
    for (int i = 0; i < 4; ++i) acc[i] = bias;

    for (int kc = 0; kc < IN_F; kc += 32) {
        __syncthreads();                  // protect sWl (and first-iter sf)
        {   // stage W[kc..kc+32][0..256): 2048 float4
            const float4* wsrc = (const float4*)(W + (size_t)kc * OUT_F);
            float4* wdst = (float4*)sWl;
            for (int i = tid; i < 32 * OUT_F / 4; i += 256) wdst[i] = wsrc[i];
        }
        __syncthreads();
#pragma unroll
        for (int kk = 0; kk < 32; kk += 4) {
            const float4 w0 = *(const float4*)&sWl[(kk + 0) * OUT_F + cg * 4];
            const float4 w1 = *(const float4*)&sWl[(kk + 1) * OUT_F + cg * 4];
            const float4 w2 = *(const float4*)&sWl[(kk + 2) * OUT_F + cg * 4];
            const float4 w3 = *(const float4*)&sWl[(kk + 3) * OUT_F + cg * 4];
#pragma unroll
            for (int i = 0; i < 4; ++i) {
                const float4 f = *(const float4*)&sf[rg * 4 + i][kc + kk]; // broadcast
                acc[i].x = fmaf(f.x, w0.x, acc[i].x);
                acc[i].y = fmaf(f.x, w0.y, acc[i].y);
                acc[i].z = fmaf(f.x, w0.z, acc[i].z);
                acc[i].w = fmaf(f.x, w0.w, acc[i].w);
                acc[i].x = fmaf(f.y, w1.x, acc[i].x);
                acc[i].y = fmaf(f.y, w1.y, acc[i].y);
                acc[i].z = fmaf(f.y, w1.z, acc[i].z);
                acc[i].w = fmaf(f.y, w1.w, acc[i].w);
                acc[i].x = fmaf(f.z, w2.x, acc[i].x);
                acc[i].y = fmaf(f.z, w2.y, acc[i].y);
                acc[i].z = fmaf(f.z, w2.z, acc[i].z);
                acc[i].w = fmaf(f.z, w2.w, acc[i].w);
                acc[i].x = fmaf(f.w, w3.x, acc[i].x);
                acc[i].y = fmaf(f.w, w3.y, acc[i].y);
                acc[i].z = fmaf(f.w, w3.z, acc[i].z);
                acc[i].w = fmaf(f.w, w3.w, acc[i].w);
            }
        }
    }

    // bf16 Wh, split-plane layout (RTN)
    const int hh = cg >> 5;               // feature half: cols cg*4 >= 128 ?
    const int f4 = cg & 31;               // ushort4 slot within half
#pragma unroll
    for (int i = 0; i < 4; ++i) {
        const int row = nb + rg * 4 + i;
        ushort4 pk;
        pk.x = f2bf_rtn(acc[i].x); pk.y = f2bf_rtn(acc[i].y);
        pk.z = f2bf_rtn(acc[i].z); pk.w = f2bf_rtn(acc[i].w);
        ((ushort4*)(WhB + ((size_t)(hh * N_NODES + row) << 7)))[f4] = pk;
    }

    // ds/dd: in-register dot + full-wave shuffle reduce (rows wave-uniform)
    const float4 was4 = ((const float4*)Was)[cg];
    const float4 wad4 = ((const float4*)Wad)[cg];
#pragma unroll
    for (int i = 0; i < 4; ++i) {
        float s = acc[i].x * was4.x + acc[i].y * was4.y + acc[i].z * was4.z + acc[i].w * was4.w;
        float d = acc[i].x * wad4.x + acc[i].y * wad4.y + acc[i].z * wad4.z + acc[i].w * wad4.w;
        for (int m = 32; m; m >>= 1) { s += __shfl_xor(s, m); d += __shfl_xor(d, m); }
        if (cg == 0) { const int row = nb + rg * 4 + i; ds[row] = s; dd[row] = d; }
    }

    // column sums -> S (one atomic per col per block)
    float4 cp;
    cp.x = acc[0].x + acc[1].x + acc[2].x + acc[3].x;
    cp.y = acc[0].y + acc[1].y + acc[2].y + acc[3].y;
    cp.z = acc[0].z + acc[1].z + acc[2].z + acc[3].z;
    cp.w = acc[0].w + acc[1].w + acc[2].w + acc[3].w;
    *(float4*)&psum[rg][cg * 4] = cp;
    __syncthreads();
    atomicAdd(&S[tid], psum[0][tid] + psum[1][tid] + psum[2][tid] + psum[3][tid]);
}

// ---------------------------------------------------------------------------
// K2: per-edge logit computed inline + scatter into fixed-CAP row buckets.
// One atomic per touch; one int4 (col, ord, e, pad) store per touch.
// ord encodes jnp scatter sequence: phase1 (u,v)=i, phase2 (v,u)=N_EDGES+i.
// ---------------------------------------------------------------------------
__global__ void scatter_kernel(const int* __restrict__ eu, const int* __restrict__ ev,
                               const float* __restrict__ ds, const float* __restrict__ dd,
                               const float* __restrict__ batt, int* __restrict__ cnt,
                               int4* __restrict__ slots) {
    const int i = blockIdx.x * blockDim.x + threadIdx.x;
    if (i >= N_EDGES) return;
    const int u = eu[i], v = ev[i];
    const float e = ds[u] + dd[v] + batt[0];
    const int ei = __float_as_int(e);
    const int p = atomicAdd(&cnt[u], 1);
    if (p < CAP) { int4 a; a.x = v; a.y = i;           a.z = ei; a.w = 0; slots[(size_t)u * CAP + p] = a; }
    const int q = atomicAdd(&cnt[v], 1);
    if (q < CAP) { int4 c; c.x = u; c.y = N_EDGES + i; c.z = ei; c.w = 0; slots[(size_t)v * CAP + q] = c; }
}

// ---------------------------------------------------------------------------
// K3: per-(row, feature-half) dedupe + softmax-weighted gather + ELU.
// Block = 128 threads, grid = 20000: r = bid>>1, h = bid&1. blockIdx%8 XCD
// round-robin puts each 2.56 MB WhB plane on its own set of 4 XCD L2s.
// out[r] = elu((S + sum w_j*Wh[c_j]) / (N + sum w_j)), w = exp(lrelu(e)) - 1.
// ---------------------------------------------------------------------------
__global__ __launch_bounds__(128) void row_kernel(
    const unsigned short* __restrict__ WhB, const float* __restrict__ S,
    const int* __restrict__ cnt, const int4* __restrict__ slots,
    float* __restrict__ out)
{
    __shared__ float sw[CAP];
    __shared__ int   scol[CAP];
    __shared__ int   sord[CAP];
    const int bid = blockIdx.x;
    const int r = bid >> 1, h = bid & 1;
    const int tid = threadIdx.x;
    int k = cnt[r];
    if (k > CAP) k = CAP;
    const int4* src = slots + (size_t)r * CAP;
    {   // stage + leaky_relu + expm1 (pad entries inert: w=0)
        const int j = tid;                // CAP == blockDim.x
        if (j < k) {
            const int4 t = src[j];
            scol[j] = t.x; sord[j] = t.y;
            const float x = __int_as_float(t.z);
            const float l = x >= 0.f ? x : SLOPE * x;
            sw[j] = __expf(l) - 1.f;
        } else { scol[j] = 0; sord[j] = -1; sw[j] = 0.f; }
    }
    __syncthreads();
    // dedupe: zero every touch that is not the last (max-order) of its column
    if (tid < k) {
        const int c = scol[tid], o = sord[tid];
        for (int t = 0; t < k; ++t)
            if (scol[t] == c && sord[t] > o) { sw[tid] = 0.f; break; }
    }
    __syncthreads();

    const int k4 = (k + 3) & ~3;
    float acc0 = S[h * 128 + tid], acc1 = 0.f, acc2 = 0.f, acc3 = 0.f;
    float s0 = 0.f, s1 = 0.f, s2 = 0.f, s3 = 0.f;
    const unsigned short* wb = WhB + ((size_t)h * N_NODES << 7) + tid;
    for (int j = 0; j < k4; j += 4) {
        const float4 w4 = *(const float4*)&sw[j];    // LDS b128 broadcast
        const int4   c4 = *(const int4*)&scol[j];    // LDS b128 broadcast
        const float x0 = __uint_as_float((unsigned)wb[(size_t)c4.x << 7] << 16);
        const float x1 = __uint_as_float((unsigned)wb[(size_t)c4.y << 7] << 16);
        const float x2 = __uint_as_float((unsigned)wb[(size_t)c4.z << 7] << 16);
        const float x3 = __uint_as_float((unsigned)wb[(size_t)c4.w << 7] << 16);
        acc0 = fmaf(w4.x, x0, acc0); s0 += w4.x;
        acc1 = fmaf(w4.y, x1, acc1); s1 += w4.y;
        acc2 = fmaf(w4.z, x2, acc2); s2 += w4.z;
        acc3 = fmaf(w4.w, x3, acc3); s3 += w4.w;
    }
    const float wsum = (s0 + s1) + (s2 + s3);
    const float a = ((acc0 + acc1) + (acc2 + acc3)) / ((float)N_NODES + wsum);
    out[(size_t)r * OUT_F + h * 128 + tid] = a > 0.f ? a : expm1f(a);
}

// ---------------------------------------------------------------------------
extern "C" void kernel_launch(void* const* d_in, const int* in_sizes, int n_in,
                              void* d_out, int out_size, void* d_ws, size_t ws_size,
                              hipStream_t stream) {
    const float* feat = (const float*)d_in[0];
    const int*   eu   = (const int*)d_in[1];
    const int*   ev   = (const int*)d_in[2];
    const float* W    = (const float*)d_in[3];
    const float* blin = (const float*)d_in[4];
    const float* Was  = (const float*)d_in[5];
    const float* Wad  = (const float*)d_in[6];
    const float* batt = (const float*)d_in[7];
    float* out = (float*)d_out;

    // workspace layout (16B-aligned slices)
    char* p = (char*)d_ws;
    int4* slots = (int4*)p;                   p += (size_t)N_NODES * CAP * 16;      // 20.48 MB
    unsigned short* WhB = (unsigned short*)p; p += (size_t)2 * N_NODES * 128 * 2;   // 5.12 MB
    float* S    = (float*)p;                  p += OUT_F * 4;                       // 1 KB
    int*   cnt  = (int*)p;                    p += N_NODES * 4;                     // 40 KB (contiguous with S)
    float* dsv  = (float*)p;                  p += N_NODES * 4;
    float* ddv  = (float*)p;                  p += N_NODES * 4;

    hipMemsetAsync(S, 0, OUT_F * sizeof(float) + N_NODES * sizeof(int), stream);  // S + cnt

    wh_kernel     <<<N_NODES / 16,          256, 0, stream>>>(feat, W, blin, Was, Wad, WhB, dsv, ddv, S);
    scatter_kernel<<<(N_EDGES + 255) / 256, 256, 0, stream>>>(eu, ev, dsv, ddv, batt, cnt, slots);
    row_kernel    <<<2 * N_NODES,           128, 0, stream>>>(WhB, S, cnt, slots, out);
}

// Round 4
// 237.598 us; speedup vs baseline: 1.6942x; 1.1816x over previous
//
#include <hip/hip_runtime.h>
#include <math.h>

#define N_NODES 10000
#define N_EDGES 320000
#define IN_F 256
#define OUT_F 256
#define SLOPE 0.2f
#define CAP 128   // per-row touch capacity; degree ~ Poisson(64), P(>128) < 1e-14

__device__ __forceinline__ unsigned short f2bf_rtn(float x) {
    unsigned int u = __float_as_uint(x);
    u = (u + 0x7FFFu + ((u >> 16) & 1u)) >> 16;
    return (unsigned short)u;
}

// ---------------------------------------------------------------------------
// K1: fused Wh GEMM + bf16 split-plane copy + projections (ds,dd) + colsum S.
// Block = 16 rows x 256 cols, 256 threads; wave rg owns rows rg*4..rg*4+3.
// W is read straight from global (L2-resident 256 KB, coalesced float4) —
// no LDS staging, ONE barrier total, LDS pipe reserved for sf broadcasts.
// WhB layout: plane h = WhB[(h*N + node)*128 + f] (2.56 MB per plane).
// ---------------------------------------------------------------------------
__global__ __launch_bounds__(256) void wh_kernel(
    const float* __restrict__ feat, const float* __restrict__ W,
    const float* __restrict__ b, const float* __restrict__ Was,
    const float* __restrict__ Wad, unsigned short* __restrict__ WhB,
    float* __restrict__ ds, float* __restrict__ dd, float* __restrict__ S)
{
    __shared__ float sf[16][IN_F];        // 16 KB feature tile
    __shared__ float psum[4][OUT_F];      // 4 KB column-sum partials
    const int nb  = blockIdx.x * 16;
    const int tid = threadIdx.x;
    const int rg  = tid >> 6;             // wave id -> row group
    const int cg  = tid & 63;             // lane -> col group (4 cols)

    {   // stage features (coalesced float4)
        const float4* src = (const float4*)(feat + (size_t)nb * IN_F);
        float4* dst = (float4*)sf;
        for (int i = tid; i < 16 * IN_F / 4; i += 256) dst[i] = src[i];
    }
    __syncthreads();                      // the only barrier before the tail

    float4 acc[4];
    const float4 bias = ((const float4*)b)[cg];
#pragma unroll
    for (int i = 0; i < 4; ++i) acc[i] = bias;

    const float4* Wg = (const float4*)W;  // W[k][0..255] -> Wg[k*64 + cg]
#pragma unroll 2
    for (int kc = 0; kc < IN_F; kc += 4) {
        const float4 w0 = Wg[(kc + 0) * 64 + cg];
        const float4 w1 = Wg[(kc + 1) * 64 + cg];
        const float4 w2 = Wg[(kc + 2) * 64 + cg];
        const float4 w3 = Wg[(kc + 3) * 64 + cg];
#pragma unroll
        for (int i = 0; i < 4; ++i) {
            const float4 f = *(const float4*)&sf[rg * 4 + i][kc];  // wave-uniform broadcast
            acc[i].x = fmaf(f.x, w0.x, acc[i].x);
            acc[i].y = fmaf(f.x, w0.y, acc[i].y);
            acc[i].z = fmaf(f.x, w0.z, acc[i].z);
            acc[i].w = fmaf(f.x, w0.w, acc[i].w);
            acc[i].x = fmaf(f.y, w1.x, acc[i].x);
            acc[i].y = fmaf(f.y, w1.y, acc[i].y);
            acc[i].z = fmaf(f.y, w1.z, acc[i].z);
            acc[i].w = fmaf(f.y, w1.w, acc[i].w);
            acc[i].x = fmaf(f.z, w2.x, acc[i].x);
            acc[i].y = fmaf(f.z, w2.y, acc[i].y);
            acc[i].z = fmaf(f.z, w2.z, acc[i].z);
            acc[i].w = fmaf(f.z, w2.w, acc[i].w);
            acc[i].x = fmaf(f.w, w3.x, acc[i].x);
            acc[i].y = fmaf(f.w, w3.y, acc[i].y);
            acc[i].z = fmaf(f.w, w3.z, acc[i].z);
            acc[i].w = fmaf(f.w, w3.w, acc[i].w);
        }
    }

    // bf16 Wh, split-plane layout (RTN)
    const int hh = cg >> 5;               // feature half
    const int f4 = cg & 31;               // ushort4 slot within half
#pragma unroll
    for (int i = 0; i < 4; ++i) {
        const int row = nb + rg * 4 + i;
        ushort4 pk;
        pk.x = f2bf_rtn(acc[i].x); pk.y = f2bf_rtn(acc[i].y);
        pk.z = f2bf_rtn(acc[i].z); pk.w = f2bf_rtn(acc[i].w);
        ((ushort4*)(WhB + ((size_t)(hh * N_NODES + row) << 7)))[f4] = pk;
    }

    // ds/dd: in-register dot + full-wave shuffle reduce (rows wave-uniform)
    const float4 was4 = ((const float4*)Was)[cg];
    const float4 wad4 = ((const float4*)Wad)[cg];
#pragma unroll
    for (int i = 0; i < 4; ++i) {
        float s = acc[i].x * was4.x + acc[i].y * was4.y + acc[i].z * was4.z + acc[i].w * was4.w;
        float d = acc[i].x * wad4.x + acc[i].y * wad4.y + acc[i].z * wad4.z + acc[i].w * wad4.w;
        for (int m = 32; m; m >>= 1) { s += __shfl_xor(s, m); d += __shfl_xor(d, m); }
        if (cg == 0) { const int row = nb + rg * 4 + i; ds[row] = s; dd[row] = d; }
    }

    // column sums -> S (one atomic per col per block)
    float4 cp;
    cp.x = acc[0].x + acc[1].x + acc[2].x + acc[3].x;
    cp.y = acc[0].y + acc[1].y + acc[2].y + acc[3].y;
    cp.z = acc[0].z + acc[1].z + acc[2].z + acc[3].z;
    cp.w = acc[0].w + acc[1].w + acc[2].w + acc[3].w;
    *(float4*)&psum[rg][cg * 4] = cp;
    __syncthreads();
    atomicAdd(&S[tid], psum[0][tid] + psum[1][tid] + psum[2][tid] + psum[3][tid]);
}

// ---------------------------------------------------------------------------
// K2: per-edge logit computed inline + scatter into fixed-CAP row buckets.
// ord encodes jnp scatter sequence: phase1 (u,v)=i, phase2 (v,u)=N_EDGES+i.
// ---------------------------------------------------------------------------
__global__ void scatter_kernel(const int* __restrict__ eu, const int* __restrict__ ev,
                               const float* __restrict__ ds, const float* __restrict__ dd,
                               const float* __restrict__ batt, int* __restrict__ cnt,
                               int4* __restrict__ slots) {
    const int i = blockIdx.x * blockDim.x + threadIdx.x;
    if (i >= N_EDGES) return;
    const int u = eu[i], v = ev[i];
    const float e = ds[u] + dd[v] + batt[0];
    const int ei = __float_as_int(e);
    const int p = atomicAdd(&cnt[u], 1);
    if (p < CAP) { int4 a; a.x = v; a.y = i;           a.z = ei; a.w = 0; slots[(size_t)u * CAP + p] = a; }
    const int q = atomicAdd(&cnt[v], 1);
    if (q < CAP) { int4 c; c.x = u; c.y = N_EDGES + i; c.z = ei; c.w = 0; slots[(size_t)v * CAP + q] = c; }
}

// ---------------------------------------------------------------------------
// K3: per-row dedupe + softmax-weighted gather + ELU. One block per row,
// 128 threads = 2 waves; wave w = feature plane w; lane l owns feats
// {w*128+2l, w*128+2l+1} via ONE uint gather load per touch. 8-touch unroll
// -> 8 independent loads in flight per wave; stage/dedupe/exp done once.
// out[r] = elu((S + sum w_j*Wh[c_j]) / (N + sum w_j)), w = exp(lrelu(e)) - 1.
// ---------------------------------------------------------------------------
__global__ __launch_bounds__(128) void row_kernel(
    const unsigned short* __restrict__ WhB, const float* __restrict__ S,
    const int* __restrict__ cnt, const int4* __restrict__ slots,
    float* __restrict__ out)
{
    __shared__ float sw[CAP];
    __shared__ int   scol[CAP];
    __shared__ int   sord[CAP];
    const int r   = blockIdx.x;
    const int tid = threadIdx.x;          // 0..127 == CAP
    const int w   = tid >> 6;             // plane
    const int l   = tid & 63;             // lane
    int k = cnt[r];
    if (k > CAP) k = CAP;
    if (tid < k) {
        const int4 t = slots[(size_t)r * CAP + tid];
        scol[tid] = t.x; sord[tid] = t.y;
        const float x = __int_as_float(t.z);
        const float lr = x >= 0.f ? x : SLOPE * x;
        sw[tid] = __expf(lr) - 1.f;
    } else { scol[tid] = 0; sord[tid] = -1; sw[tid] = 0.f; }  // pad: w=0 inert
    __syncthreads();
    // dedupe: zero every touch that is not the last (max-order) of its column
    if (tid < k) {
        const int c = scol[tid], o = sord[tid];
        for (int t = 0; t < k; ++t)
            if (scol[t] == c && sord[t] > o) { sw[tid] = 0.f; break; }
    }
    __syncthreads();

    const int k8 = (k + 7) & ~7;
    const unsigned int* wp = (const unsigned int*)(WhB + ((size_t)w * N_NODES << 7)) + l;
    float aL0 = 0.f, aL1 = 0.f, aL2 = 0.f, aL3 = 0.f;
    float aH0 = 0.f, aH1 = 0.f, aH2 = 0.f, aH3 = 0.f;
    float s0 = 0.f, s1 = 0.f, s2 = 0.f, s3 = 0.f;
    for (int j = 0; j < k8; j += 8) {
        const float4 wa = *(const float4*)&sw[j];      // LDS b128 broadcast
        const float4 wb = *(const float4*)&sw[j + 4];
        const int4   ca = *(const int4*)&scol[j];
        const int4   cb = *(const int4*)&scol[j + 4];
        const unsigned int u0 = wp[(size_t)ca.x << 6]; // 8 independent 4B gathers
        const unsigned int u1 = wp[(size_t)ca.y << 6];
        const unsigned int u2 = wp[(size_t)ca.z << 6];
        const unsigned int u3 = wp[(size_t)ca.w << 6];
        const unsigned int u4 = wp[(size_t)cb.x << 6];
        const unsigned int u5 = wp[(size_t)cb.y << 6];
        const unsigned int u6 = wp[(size_t)cb.z << 6];
        const unsigned int u7 = wp[(size_t)cb.w << 6];
        aL0 = fmaf(wa.x, __uint_as_float(u0 << 16), aL0);
        aH0 = fmaf(wa.x, __uint_as_float(u0 & 0xFFFF0000u), aH0);
        aL1 = fmaf(wa.y, __uint_as_float(u1 << 16), aL1);
        aH1 = fmaf(wa.y, __uint_as_float(u1 & 0xFFFF0000u), aH1);
        aL2 = fmaf(wa.z, __uint_as_float(u2 << 16), aL2);
        aH2 = fmaf(wa.z, __uint_as_float(u2 & 0xFFFF0000u), aH2);
        aL3 = fmaf(wa.w, __uint_as_float(u3 << 16), aL3);
        aH3 = fmaf(wa.w, __uint_as_float(u3 & 0xFFFF0000u), aH3);
        aL0 = fmaf(wb.x, __uint_as_float(u4 << 16), aL0);
        aH0 = fmaf(wb.x, __uint_as_float(u4 & 0xFFFF0000u), aH0);
        aL1 = fmaf(wb.y, __uint_as_float(u5 << 16), aL1);
        aH1 = fmaf(wb.y, __uint_as_float(u5 & 0xFFFF0000u), aH1);
        aL2 = fmaf(wb.z, __uint_as_float(u6 << 16), aL2);
        aH2 = fmaf(wb.z, __uint_as_float(u6 & 0xFFFF0000u), aH2);
        aL3 = fmaf(wb.w, __uint_as_float(u7 << 16), aL3);
        aH3 = fmaf(wb.w, __uint_as_float(u7 & 0xFFFF0000u), aH3);
        s0 += wa.x + wb.x;
        s1 += wa.y + wb.y;
        s2 += wa.z + wb.z;
        s3 += wa.w + wb.w;
    }
    const float wsum = (s0 + s1) + (s2 + s3);
    const float Z = (float)N_NODES + wsum;
    const float2 S2 = *(const float2*)&S[(w << 7) + (l << 1)];
    const float aL = (S2.x + ((aL0 + aL1) + (aL2 + aL3))) / Z;
    const float aH = (S2.y + ((aH0 + aH1) + (aH2 + aH3))) / Z;
    float2 o;
    o.x = aL > 0.f ? aL : expm1f(aL);
    o.y = aH > 0.f ? aH : expm1f(aH);
    *(float2*)&out[((size_t)r << 8) + (w << 7) + (l << 1)] = o;
}

// ---------------------------------------------------------------------------
extern "C" void kernel_launch(void* const* d_in, const int* in_sizes, int n_in,
                              void* d_out, int out_size, void* d_ws, size_t ws_size,
                              hipStream_t stream) {
    const float* feat = (const float*)d_in[0];
    const int*   eu   = (const int*)d_in[1];
    const int*   ev   = (const int*)d_in[2];
    const float* W    = (const float*)d_in[3];
    const float* blin = (const float*)d_in[4];
    const float* Was  = (const float*)d_in[5];
    const float* Wad  = (const float*)d_in[6];
    const float* batt = (const float*)d_in[7];
    float* out = (float*)d_out;

    // workspace layout (16B-aligned slices)
    char* p = (char*)d_ws;
    int4* slots = (int4*)p;                   p += (size_t)N_NODES * CAP * 16;      // 20.48 MB
    unsigned short* WhB = (unsigned short*)p; p += (size_t)2 * N_NODES * 128 * 2;   // 5.12 MB
    float* S    = (float*)p;                  p += OUT_F * 4;                       // 1 KB
    int*   cnt  = (int*)p;                    p += N_NODES * 4;                     // 40 KB (contiguous with S)
    float* dsv  = (float*)p;                  p += N_NODES * 4;
    float* ddv  = (float*)p;                  p += N_NODES * 4;

    hipMemsetAsync(S, 0, OUT_F * sizeof(float) + N_NODES * sizeof(int), stream);  // S + cnt

    wh_kernel     <<<N_NODES / 16,          256, 0, stream>>>(feat, W, blin, Was, Wad, WhB, dsv, ddv, S);
    scatter_kernel<<<(N_EDGES + 255) / 256, 256, 0, stream>>>(eu, ev, dsv, ddv, batt, cnt, slots);
    row_kernel    <<<N_NODES,               128, 0, stream>>>(WhB, S, cnt, slots, out);
}

// Round 6
// 231.156 us; speedup vs baseline: 1.7414x; 1.0279x over previous
//
#include <hip/hip_runtime.h>
#include <math.h>

#define N_NODES 10000
#define N_EDGES 320000
#define IN_F 256
#define OUT_F 256
#define SLOPE 0.2f
#define CAP 128   // per-row touch capacity; degree ~ Poisson(64), P(>128) < 1e-14

__device__ __forceinline__ unsigned short f2bf_rtn(float x) {
    unsigned int u = __float_as_uint(x);
    u = (u + 0x7FFFu + ((u >> 16) & 1u)) >> 16;
    return (unsigned short)u;
}
__device__ __forceinline__ float bf_lo(unsigned int u) { return __uint_as_float(u << 16); }
__device__ __forceinline__ float bf_hi(unsigned int u) { return __uint_as_float(u & 0xFFFF0000u); }

// ---------------------------------------------------------------------------
// K1: fused Wh GEMM + bf16 copy + projections (ds,dd) + colsum S.
// 1250 blocks x 8 rows (2x the TLP of the 16-row version — round-4 showed
// occupancy 23%, VALUBusy 15%: grid starvation). Wave rg owns rows rg*2..+1.
// W read from global (L2-resident) with an explicit double-buffered register
// prefetch: 8 float4 loads issued one full K-iteration ahead of use.
// ---------------------------------------------------------------------------
__global__ __launch_bounds__(256) void wh_kernel(
    const float* __restrict__ feat, const float* __restrict__ W,
    const float* __restrict__ b, const float* __restrict__ Was,
    const float* __restrict__ Wad, unsigned short* __restrict__ WhB,
    float* __restrict__ ds, float* __restrict__ dd, float* __restrict__ S)
{
    __shared__ float sf[8][IN_F];         // 8 KB feature tile
    __shared__ float psum[4][OUT_F];      // 4 KB column-sum partials
    const int nb  = blockIdx.x * 8;
    const int tid = threadIdx.x;
    const int rg  = tid >> 6;             // wave id -> row pair
    const int cg  = tid & 63;             // lane -> col group (4 cols)

    {   // stage features (coalesced float4, 2 per thread)
        const float4* src = (const float4*)(feat + (size_t)nb * IN_F);
        float4* dst = (float4*)sf;
        dst[tid]       = src[tid];
        dst[tid + 256] = src[tid + 256];
    }
    __syncthreads();

    float4 acc[2];
    const float4 bias = ((const float4*)b)[cg];
    acc[0] = bias; acc[1] = bias;

    const float4* Wg = (const float4*)W;  // W[k][0..255] -> Wg[k*64 + cg]
    float4 wc[8], wn[8];
#pragma unroll
    for (int j = 0; j < 8; ++j) wc[j] = Wg[j * 64 + cg];

    for (int kc = 0; kc < IN_F; kc += 8) {
        const int kn = kc + 8;
        if (kn < IN_F) {
#pragma unroll
            for (int j = 0; j < 8; ++j) wn[j] = Wg[(kn + j) * 64 + cg];
        }
#pragma unroll
        for (int i = 0; i < 2; ++i) {
            const float4 fA = *(const float4*)&sf[rg * 2 + i][kc];      // broadcast
            const float4 fB = *(const float4*)&sf[rg * 2 + i][kc + 4];  // broadcast
            acc[i].x = fmaf(fA.x, wc[0].x, acc[i].x);
            acc[i].y = fmaf(fA.x, wc[0].y, acc[i].y);
            acc[i].z = fmaf(fA.x, wc[0].z, acc[i].z);
            acc[i].w = fmaf(fA.x, wc[0].w, acc[i].w);
            acc[i].x = fmaf(fA.y, wc[1].x, acc[i].x);
            acc[i].y = fmaf(fA.y, wc[1].y, acc[i].y);
            acc[i].z = fmaf(fA.y, wc[1].z, acc[i].z);
            acc[i].w = fmaf(fA.y, wc[1].w, acc[i].w);
            acc[i].x = fmaf(fA.z, wc[2].x, acc[i].x);
            acc[i].y = fmaf(fA.z, wc[2].y, acc[i].y);
            acc[i].z = fmaf(fA.z, wc[2].z, acc[i].z);
            acc[i].w = fmaf(fA.z, wc[2].w, acc[i].w);
            acc[i].x = fmaf(fA.w, wc[3].x, acc[i].x);
            acc[i].y = fmaf(fA.w, wc[3].y, acc[i].y);
            acc[i].z = fmaf(fA.w, wc[3].z, acc[i].z);
            acc[i].w = fmaf(fA.w, wc[3].w, acc[i].w);
            acc[i].x = fmaf(fB.x, wc[4].x, acc[i].x);
            acc[i].y = fmaf(fB.x, wc[4].y, acc[i].y);
            acc[i].z = fmaf(fB.x, wc[4].z, acc[i].z);
            acc[i].w = fmaf(fB.x, wc[4].w, acc[i].w);
            acc[i].x = fmaf(fB.y, wc[5].x, acc[i].x);
            acc[i].y = fmaf(fB.y, wc[5].y, acc[i].y);
            acc[i].z = fmaf(fB.y, wc[5].z, acc[i].z);
            acc[i].w = fmaf(fB.y, wc[5].w, acc[i].w);
            acc[i].x = fmaf(fB.z, wc[6].x, acc[i].x);
            acc[i].y = fmaf(fB.z, wc[6].y, acc[i].y);
            acc[i].z = fmaf(fB.z, wc[6].z, acc[i].z);
            acc[i].w = fmaf(fB.z, wc[6].w, acc[i].w);
            acc[i].x = fmaf(fB.w, wc[7].x, acc[i].x);
            acc[i].y = fmaf(fB.w, wc[7].y, acc[i].y);
            acc[i].z = fmaf(fB.w, wc[7].z, acc[i].z);
            acc[i].w = fmaf(fB.w, wc[7].w, acc[i].w);
        }
#pragma unroll
        for (int j = 0; j < 8; ++j) wc[j] = wn[j];
    }

    // bf16 Wh, unified layout WhB[row][256]
#pragma unroll
    for (int i = 0; i < 2; ++i) {
        const int row = nb + rg * 2 + i;
        ushort4 pk;
        pk.x = f2bf_rtn(acc[i].x); pk.y = f2bf_rtn(acc[i].y);
        pk.z = f2bf_rtn(acc[i].z); pk.w = f2bf_rtn(acc[i].w);
        ((ushort4*)WhB)[(size_t)row * 64 + cg] = pk;
    }

    // ds/dd: in-register dot + full-wave shuffle reduce (rows wave-uniform)
    const float4 was4 = ((const float4*)Was)[cg];
    const float4 wad4 = ((const float4*)Wad)[cg];
#pragma unroll
    for (int i = 0; i < 2; ++i) {
        float s = acc[i].x * was4.x + acc[i].y * was4.y + acc[i].z * was4.z + acc[i].w * was4.w;
        float d = acc[i].x * wad4.x + acc[i].y * wad4.y + acc[i].z * wad4.z + acc[i].w * wad4.w;
        for (int m = 32; m; m >>= 1) { s += __shfl_xor(s, m); d += __shfl_xor(d, m); }
        if (cg == 0) { const int row = nb + rg * 2 + i; ds[row] = s; dd[row] = d; }
    }

    // column sums -> S (one atomic per col per block)
    float4 cp;
    cp.x = acc[0].x + acc[1].x;
    cp.y = acc[0].y + acc[1].y;
    cp.z = acc[0].z + acc[1].z;
    cp.w = acc[0].w + acc[1].w;
    *(float4*)&psum[rg][cg * 4] = cp;
    __syncthreads();
    atomicAdd(&S[tid], psum[0][tid] + psum[1][tid] + psum[2][tid] + psum[3][tid]);
}

// ---------------------------------------------------------------------------
// K2: per-edge logit computed inline + scatter into fixed-CAP row buckets.
// ord encodes jnp scatter sequence: phase1 (u,v)=i, phase2 (v,u)=N_EDGES+i.
// ---------------------------------------------------------------------------
__global__ void scatter_kernel(const int* __restrict__ eu, const int* __restrict__ ev,
                               const float* __restrict__ ds, const float* __restrict__ dd,
                               const float* __restrict__ batt, int* __restrict__ cnt,
                               int4* __restrict__ slots) {
    const int i = blockIdx.x * blockDim.x + threadIdx.x;
    if (i >= N_EDGES) return;
    const int u = eu[i], v = ev[i];
    const float e = ds[u] + dd[v] + batt[0];
    const int ei = __float_as_int(e);
    const int p = atomicAdd(&cnt[u], 1);
    if (p < CAP) { int4 a; a.x = v; a.y = i;           a.z = ei; a.w = 0; slots[(size_t)u * CAP + p] = a; }
    const int q = atomicAdd(&cnt[v], 1);
    if (q < CAP) { int4 c; c.x = u; c.y = N_EDGES + i; c.z = ei; c.w = 0; slots[(size_t)v * CAP + q] = c; }
}

// ---------------------------------------------------------------------------
// K3: per-row dedupe + softmax-weighted gather + ELU.
// One block (256 thr = 4 waves) per row. ONE wave covers the full 256-feature
// row: lane l holds feats 4l..4l+3 via one uint2 (4 bf16) gather load. Wave w
// owns touches [w*kq, w*kq+kq); partials combined through LDS at the end.
// out[r] = elu((S + sum w_j*Wh[c_j]) / (N + sum w_j)), w = exp(lrelu(e)) - 1.
// ---------------------------------------------------------------------------
__global__ __launch_bounds__(256) void row_kernel(
    const unsigned short* __restrict__ WhB, const float* __restrict__ S,
    const int* __restrict__ cnt, const int4* __restrict__ slots,
    float* __restrict__ out)
{
    __shared__ __attribute__((aligned(16))) float sw[CAP];
    __shared__ __attribute__((aligned(16))) int   scol[CAP + 4];
    __shared__ __attribute__((aligned(16))) int   sord[CAP + 4];
    __shared__ float comb[3][64][4];
    __shared__ float wspart[4];
    const int r   = blockIdx.x;
    const int tid = threadIdx.x;
    const int w   = tid >> 6;             // wave -> touch quarter
    const int l   = tid & 63;             // lane -> 4 features
    int k = cnt[r];
    if (k > CAP) k = CAP;
    if (tid < CAP) {
        if (tid < k) {
            const int4 t = slots[(size_t)r * CAP + tid];
            scol[tid] = t.x; sord[tid] = t.y;
            const float x = __int_as_float(t.z);
            const float lr = x >= 0.f ? x : SLOPE * x;
            sw[tid] = __expf(lr) - 1.f;
        } else { scol[tid] = 0; sord[tid] = -1; sw[tid] = 0.f; }
    } else if (tid < CAP + 4) {           // pad for int4 dedupe overrun
        scol[tid] = 0; sord[tid] = -1;
    }
    __syncthreads();
    // dedupe: zero every touch that is not the last (max-order) of its column
    if (tid < k) {
        const int c = scol[tid], o = sord[tid];
        const int4* s4 = (const int4*)scol;
        const int4* o4 = (const int4*)sord;
        const int kk4 = (k + 3) >> 2;
        bool dup = false;
        for (int t = 0; t < kk4; ++t) {
            const int4 cc = s4[t];
            const int4 oo = o4[t];
            dup = dup | (cc.x == c && oo.x > o) | (cc.y == c && oo.y > o)
                      | (cc.z == c && oo.z > o) | (cc.w == c && oo.w > o);
        }
        if (dup) sw[tid] = 0.f;
    }
    __syncthreads();

    const int k32 = (k + 31) & ~31;
    const int kq  = k32 >> 2;             // per-wave touches, multiple of 8
    const int j0  = w * kq;
    const uint2* wp = (const uint2*)WhB + l;   // row stride = 64 uint2
    float a0 = 0.f, a1 = 0.f, a2 = 0.f, a3 = 0.f;
    float b0 = 0.f, b1 = 0.f, b2 = 0.f, b3 = 0.f;
    float s = 0.f;
    for (int j = j0; j < j0 + kq; j += 8) {
        const float4 wa = *(const float4*)&sw[j];      // LDS b128 broadcast
        const float4 wb = *(const float4*)&sw[j + 4];
        const int4   ca = *(const int4*)&scol[j];
        const int4   cb = *(const int4*)&scol[j + 4];
        const uint2 u0 = wp[(size_t)ca.x << 6];        // 8 independent 8B gathers
        const uint2 u1 = wp[(size_t)ca.y << 6];
        const uint2 u2 = wp[(size_t)ca.z << 6];
        const uint2 u3 = wp[(size_t)ca.w << 6];
        const uint2 u4 = wp[(size_t)cb.x << 6];
        const uint2 u5 = wp[(size_t)cb.y << 6];
        const uint2 u6 = wp[(size_t)cb.z << 6];
        const uint2 u7 = wp[(size_t)cb.w << 6];
        a0 = fmaf(wa.x, bf_lo(u0.x), a0); a1 = fmaf(wa.x, bf_hi(u0.x), a1);
        a2 = fmaf(wa.x, bf_lo(u0.y), a2); a3 = fmaf(wa.x, bf_hi(u0.y), a3);
        b0 = fmaf(wa.y, bf_lo(u1.x), b0); b1 = fmaf(wa.y, bf_hi(u1.x), b1);
        b2 = fmaf(wa.y, bf_lo(u1.y), b2); b3 = fmaf(wa.y, bf_hi(u1.y), b3);
        a0 = fmaf(wa.z, bf_lo(u2.x), a0); a1 = fmaf(wa.z, bf_hi(u2.x), a1);
        a2 = fmaf(wa.z, bf_lo(u2.y), a2); a3 = fmaf(wa.z, bf_hi(u2.y), a3);
        b0 = fmaf(wa.w, bf_lo(u3.x), b0); b1 = fmaf(wa.w, bf_hi(u3.x), b1);
        b2 = fmaf(wa.w, bf_lo(u3.y), b2); b3 = fmaf(wa.w, bf_hi(u3.y), b3);
        a0 = fmaf(wb.x, bf_lo(u4.x), a0); a1 = fmaf(wb.x, bf_hi(u4.x), a1);
        a2 = fmaf(wb.x, bf_lo(u4.y), a2); a3 = fmaf(wb.x, bf_hi(u4.y), a3);
        b0 = fmaf(wb.y, bf_lo(u5.x), b0); b1 = fmaf(wb.y, bf_hi(u5.x), b1);
        b2 = fmaf(wb.y, bf_lo(u5.y), b2); b3 = fmaf(wb.y, bf_hi(u5.y), b3);
        a0 = fmaf(wb.z, bf_lo(u6.x), a0); a1 = fmaf(wb.z, bf_hi(u6.x), a1);
        a2 = fmaf(wb.z, bf_lo(u6.y), a2); a3 = fmaf(wb.z, bf_hi(u6.y), a3);
        b0 = fmaf(wb.w, bf_lo(u7.x), b0); b1 = fmaf(wb.w, bf_hi(u7.x), b1);
        b2 = fmaf(wb.w, bf_lo(u7.y), b2); b3 = fmaf(wb.w, bf_hi(u7.y), b3);
        s += ((wa.x + wa.y) + (wa.z + wa.w)) + ((wb.x + wb.y) + (wb.z + wb.w));
    }
    const float p0 = a0 + b0, p1 = a1 + b1, p2 = a2 + b2, p3 = a3 + b3;
    if (w) {
        float4 p; p.x = p0; p.y = p1; p.z = p2; p.w = p3;
        *(float4*)comb[w - 1][l] = p;
        if (l == 0) wspart[w] = s;
    } else if (l == 0) wspart[0] = s;
    __syncthreads();
    if (w == 0) {
        const float4 q0 = *(const float4*)comb[0][l];
        const float4 q1 = *(const float4*)comb[1][l];
        const float4 q2 = *(const float4*)comb[2][l];
        const float Z = (float)N_NODES + ((wspart[0] + wspart[1]) + (wspart[2] + wspart[3]));
        const float4 S4 = ((const float4*)S)[l];
        const float y0 = (S4.x + ((p0 + q0.x) + (q1.x + q2.x))) / Z;
        const float y1 = (S4.y + ((p1 + q0.y) + (q1.y + q2.y))) / Z;
        const float y2 = (S4.z + ((p2 + q0.z) + (q1.z + q2.z))) / Z;
        const float y3 = (S4.w + ((p3 + q0.w) + (q1.w + q2.w))) / Z;
        float4 o;
        o.x = y0 > 0.f ? y0 : expm1f(y0);
        o.y = y1 > 0.f ? y1 : expm1f(y1);
        o.z = y2 > 0.f ? y2 : expm1f(y2);
        o.w = y3 > 0.f ? y3 : expm1f(y3);
        ((float4*)(out + (size_t)r * OUT_F))[l] = o;
    }
}

// ---------------------------------------------------------------------------
extern "C" void kernel_launch(void* const* d_in, const int* in_sizes, int n_in,
                              void* d_out, int out_size, void* d_ws, size_t ws_size,
                              hipStream_t stream) {
    const float* feat = (const float*)d_in[0];
    const int*   eu   = (const int*)d_in[1];
    const int*   ev   = (const int*)d_in[2];
    const float* W    = (const float*)d_in[3];
    const float* blin = (const float*)d_in[4];
    const float* Was  = (const float*)d_in[5];
    const float* Wad  = (const float*)d_in[6];
    const float* batt = (const float*)d_in[7];
    float* out = (float*)d_out;

    // workspace layout (16B-aligned slices)
    char* p = (char*)d_ws;
    int4* slots = (int4*)p;                   p += (size_t)N_NODES * CAP * 16;    // 20.48 MB
    unsigned short* WhB = (unsigned short*)p; p += (size_t)N_NODES * OUT_F * 2;   // 5.12 MB
    float* S    = (float*)p;                  p += OUT_F * 4;                     // 1 KB
    int*   cnt  = (int*)p;                    p += N_NODES * 4;                   // 40 KB (contiguous with S)
    float* dsv  = (float*)p;                  p += N_NODES * 4;
    float* ddv  = (float*)p;                  p += N_NODES * 4;

    hipMemsetAsync(S, 0, OUT_F * sizeof(float) + N_NODES * sizeof(int), stream);  // S + cnt

    wh_kernel     <<<N_NODES / 8,           256, 0, stream>>>(feat, W, blin, Was, Wad, WhB, dsv, ddv, S);
    scatter_kernel<<<(N_EDGES + 255) / 256, 256, 0, stream>>>(eu, ev, dsv, ddv, batt, cnt, slots);
    row_kernel    <<<N_NODES,               256, 0, stream>>>(WhB, S, cnt, slots, out);
}

// Round 9
// 201.450 us; speedup vs baseline: 1.9982x; 1.1475x over previous
//
#include <hip/hip_runtime.h>
#include <math.h>

#define N_NODES 10000
#define N_EDGES 320000
#define IN_F 256
#define OUT_F 256
#define SLOPE 0.2f
#define CAP 128   // per-row touch capacity; degree ~ Poisson(64), P(>128) < 1e-14

using f32x4 = __attribute__((ext_vector_type(4))) float;
using s16x8 = __attribute__((ext_vector_type(8))) short;
using u16x8 = __attribute__((ext_vector_type(8))) unsigned short;

__device__ __forceinline__ unsigned short f2bf_rtn(float x) {
    unsigned int u = __float_as_uint(x);
    u = (u + 0x7FFFu + ((u >> 16) & 1u)) >> 16;
    return (unsigned short)u;
}
__device__ __forceinline__ float bf_lo(unsigned int u) { return __uint_as_float(u << 16); }
__device__ __forceinline__ float bf_hi(unsigned int u) { return __uint_as_float(u & 0xFFFF0000u); }

// ---------------------------------------------------------------------------
// K0: W (K x N fp32, row-major) -> WbfT (N x K bf16, row-major) so MFMA
// B-fragments are contiguous 16B loads. 16 blocks x 64x64 tiles, LDS transpose.
// ---------------------------------------------------------------------------
__global__ __launch_bounds__(256) void wconv_kernel(const float* __restrict__ W,
                                                    unsigned short* __restrict__ WbfT) {
    __shared__ unsigned short t[64][72];   // +8 pad
    const int tid = threadIdx.x;
    const int k0 = (blockIdx.x >> 2) * 64, n0 = (blockIdx.x & 3) * 64;
#pragma unroll
    for (int i = 0; i < 16; ++i) {
        const int idx = i * 256 + tid;
        const int kk = idx >> 6, nn = idx & 63;
        t[nn][kk] = f2bf_rtn(W[(size_t)(k0 + kk) * 256 + n0 + nn]);
    }
    __syncthreads();
#pragma unroll
    for (int i = 0; i < 4; ++i) {
        const int q = i * 256 + tid;       // ushort4 id within tile
        const int nn = q >> 4, ch = q & 15;
        *(ushort4*)(WbfT + (size_t)(n0 + nn) * 256 + k0 + ch * 4) =
            *(const ushort4*)&t[nn][ch * 4];
    }
}

// ---------------------------------------------------------------------------
// K1: MFMA Wh GEMM (bf16 in, fp32 acc) + fused bf16 copy + ds/dd + colsum S.
// 625 blocks x 1 wave; wave owns 16 rows x 256 cols, K=256 (8 x 16 MFMAs).
// Each wave reads W once as bf16 (128 KB; 80 MB L2 total vs 1.28 GB fp32-VALU).
// A and B are loaded with the SAME (lane>>4, elem)->k assignment, so the MFMA
// k-sum is correct for any internal HW k-order (bijection over 32 k-slots).
// C/D layout (verified m89): col = lane&15, row = (lane>>4)*4 + reg.
// ---------------------------------------------------------------------------
__global__ __launch_bounds__(64, 1) void wh_kernel(
    const float* __restrict__ feat, const unsigned short* __restrict__ WbfT,
    const float* __restrict__ b, const float* __restrict__ Was,
    const float* __restrict__ Wad, unsigned short* __restrict__ WhB,
    float* __restrict__ ds, float* __restrict__ dd, float* __restrict__ S)
{
    __shared__ unsigned short lt[16][264];   // 16x256 bf16 tile, +8 pad (b128-aligned rows)
    const int l = threadIdx.x;
    const int c = l & 15, h = l >> 4;
    const int rbase = blockIdx.x * 16;

    float wasv[16], wadv[16];
    f32x4 acc[16];
#pragma unroll
    for (int nt = 0; nt < 16; ++nt) {
        wasv[nt] = Was[nt * 16 + c];
        wadv[nt] = Wad[nt * 16 + c];
        const float bv = b[nt * 16 + c];
        acc[nt] = (f32x4){bv, bv, bv, bv};   // bias as C-in (col = lane&15)
    }

    const float* arow = feat + (size_t)(rbase + c) * IN_F + h * 8;
    const unsigned short* bbase = WbfT + (size_t)c * 256 + h * 8;
#pragma unroll
    for (int kt = 0; kt < 8; ++kt) {
        const float4 f0 = *(const float4*)(arow + kt * 32);
        const float4 f1 = *(const float4*)(arow + kt * 32 + 4);
        s16x8 a;
        a[0] = (short)f2bf_rtn(f0.x); a[1] = (short)f2bf_rtn(f0.y);
        a[2] = (short)f2bf_rtn(f0.z); a[3] = (short)f2bf_rtn(f0.w);
        a[4] = (short)f2bf_rtn(f1.x); a[5] = (short)f2bf_rtn(f1.y);
        a[6] = (short)f2bf_rtn(f1.z); a[7] = (short)f2bf_rtn(f1.w);
        s16x8 bb[16];
#pragma unroll
        for (int nt = 0; nt < 16; ++nt)      // 16 independent 16B L2 loads in flight
            bb[nt] = *(const s16x8*)(bbase + (size_t)nt * 16 * 256 + kt * 32);
#pragma unroll
        for (int nt = 0; nt < 16; ++nt)
            acc[nt] = __builtin_amdgcn_mfma_f32_16x16x32_bf16(a, bb[nt], acc[nt], 0, 0, 0);
    }

    // ds/dd: lane partial over its 16 cols, reduce across lane&15 group
    float pds[4] = {0.f, 0.f, 0.f, 0.f}, pdd[4] = {0.f, 0.f, 0.f, 0.f};
#pragma unroll
    for (int nt = 0; nt < 16; ++nt)
#pragma unroll
        for (int r = 0; r < 4; ++r) {
            pds[r] = fmaf(acc[nt][r], wasv[nt], pds[r]);
            pdd[r] = fmaf(acc[nt][r], wadv[nt], pdd[r]);
        }
#pragma unroll
    for (int r = 0; r < 4; ++r) {
#pragma unroll
        for (int m = 1; m < 16; m <<= 1) {
            pds[r] += __shfl_xor(pds[r], m);
            pdd[r] += __shfl_xor(pdd[r], m);
        }
    }
    if (c == 0) {
#pragma unroll
        for (int r = 0; r < 4; ++r) {
            ds[rbase + h * 4 + r] = pds[r];
            dd[rbase + h * 4 + r] = pdd[r];
        }
    }

    // column sums -> S: sum 4 regs (4 rows), reduce over h groups, 16 lanes atomicAdd
#pragma unroll
    for (int nt = 0; nt < 16; ++nt) {
        float v = (acc[nt][0] + acc[nt][1]) + (acc[nt][2] + acc[nt][3]);
        v += __shfl_xor(v, 16);
        v += __shfl_xor(v, 32);
        if (h == 0) atomicAdd(&S[nt * 16 + c], v);
    }

    // WhB: bf16 tile via LDS transpose -> coalesced ushort8 stores
#pragma unroll
    for (int nt = 0; nt < 16; ++nt)
#pragma unroll
        for (int r = 0; r < 4; ++r)
            lt[h * 4 + r][nt * 16 + c] = f2bf_rtn(acc[nt][r]);
    __syncthreads();
#pragma unroll
    for (int i = 0; i < 8; ++i) {
        const int g = i * 64 + l;            // ushort8 chunk id (512 total)
        const int row = g >> 5, ch = g & 31;
        ((u16x8*)(WhB + (size_t)rbase * 256))[g] = *(const u16x8*)&lt[row][ch * 8];
    }
}

// ---------------------------------------------------------------------------
// K2: per-edge logit computed inline + scatter into fixed-CAP row buckets.
// ord encodes jnp scatter sequence: phase1 (u,v)=i, phase2 (v,u)=N_EDGES+i.
// ---------------------------------------------------------------------------
__global__ void scatter_kernel(const int* __restrict__ eu, const int* __restrict__ ev,
                               const float* __restrict__ ds, const float* __restrict__ dd,
                               const float* __restrict__ batt, int* __restrict__ cnt,
                               int4* __restrict__ slots) {
    const int i = blockIdx.x * blockDim.x + threadIdx.x;
    if (i >= N_EDGES) return;
    const int u = eu[i], v = ev[i];
    const float e = ds[u] + dd[v] + batt[0];
    const int ei = __float_as_int(e);
    const int p = atomicAdd(&cnt[u], 1);
    if (p < CAP) { int4 a; a.x = v; a.y = i;           a.z = ei; a.w = 0; slots[(size_t)u * CAP + p] = a; }
    const int q = atomicAdd(&cnt[v], 1);
    if (q < CAP) { int4 c; c.x = u; c.y = N_EDGES + i; c.z = ei; c.w = 0; slots[(size_t)v * CAP + q] = c; }
}

// ---------------------------------------------------------------------------
// K3: per-row dedupe + softmax-weighted gather + ELU.
// One block (256 thr = 4 waves) per row; wave covers the full 256-feature row
// via uint2 (4 bf16) per lane; wave w owns touch quarter w; LDS combine.
// out[r] = elu((S + sum w_j*Wh[c_j]) / (N + sum w_j)), w = exp(lrelu(e)) - 1.
// ---------------------------------------------------------------------------
__global__ __launch_bounds__(256) void row_kernel(
    const unsigned short* __restrict__ WhB, const float* __restrict__ S,
    const int* __restrict__ cnt, const int4* __restrict__ slots,
    float* __restrict__ out)
{
    __shared__ __attribute__((aligned(16))) float sw[CAP];
    __shared__ __attribute__((aligned(16))) int   scol[CAP + 4];
    __shared__ __attribute__((aligned(16))) int   sord[CAP + 4];
    __shared__ float comb[3][64][4];
    __shared__ float wspart[4];
    const int r   = blockIdx.x;
    const int tid = threadIdx.x;
    const int w   = tid >> 6;             // wave -> touch quarter
    const int l   = tid & 63;             // lane -> 4 features
    int k = cnt[r];
    if (k > CAP) k = CAP;
    if (tid < CAP) {
        if (tid < k) {
            const int4 t = slots[(size_t)r * CAP + tid];
            scol[tid] = t.x; sord[tid] = t.y;
            const float x = __int_as_float(t.z);
            const float lr = x >= 0.f ? x : SLOPE * x;
            sw[tid] = __expf(lr) - 1.f;
        } else { scol[tid] = 0; sord[tid] = -1; sw[tid] = 0.f; }
    } else if (tid < CAP + 4) {           // pad for int4 dedupe overrun
        scol[tid] = 0; sord[tid] = -1;
    }
    __syncthreads();
    // dedupe: zero every touch that is not the last (max-order) of its column
    if (tid < k) {
        const int c = scol[tid], o = sord[tid];
        const int4* s4 = (const int4*)scol;
        const int4* o4 = (const int4*)sord;
        const int kk4 = (k + 3) >> 2;
        bool dup = false;
        for (int t = 0; t < kk4; ++t) {
            const int4 cc = s4[t];
            const int4 oo = o4[t];
            dup = dup | (cc.x == c && oo.x > o) | (cc.y == c && oo.y > o)
                      | (cc.z == c && oo.z > o) | (cc.w == c && oo.w > o);
        }
        if (dup) sw[tid] = 0.f;
    }
    __syncthreads();

    const int k32 = (k + 31) & ~31;
    const int kq  = k32 >> 2;             // per-wave touches, multiple of 8
    const int j0  = w * kq;
    const uint2* wp = (const uint2*)WhB + l;   // row stride = 64 uint2
    float a0 = 0.f, a1 = 0.f, a2 = 0.f, a3 = 0.f;
    float b0 = 0.f, b1 = 0.f, b2 = 0.f, b3 = 0.f;
    float s = 0.f;
    for (int j = j0; j < j0 + kq; j += 8) {
        const float4 wa = *(const float4*)&sw[j];      // LDS b128 broadcast
        const float4 wb = *(const float4*)&sw[j + 4];
        const int4   ca = *(const int4*)&scol[j];
        const int4   cb = *(const int4*)&scol[j + 4];
        const uint2 u0 = wp[(size_t)ca.x << 6];        // 8 independent 8B gathers
        const uint2 u1 = wp[(size_t)ca.y << 6];
        const uint2 u2 = wp[(size_t)ca.z << 6];
        const uint2 u3 = wp[(size_t)ca.w << 6];
        const uint2 u4 = wp[(size_t)cb.x << 6];
        const uint2 u5 = wp[(size_t)cb.y << 6];
        const uint2 u6 = wp[(size_t)cb.z << 6];
        const uint2 u7 = wp[(size_t)cb.w << 6];
        a0 = fmaf(wa.x, bf_lo(u0.x), a0); a1 = fmaf(wa.x, bf_hi(u0.x), a1);
        a2 = fmaf(wa.x, bf_lo(u0.y), a2); a3 = fmaf(wa.x, bf_hi(u0.y), a3);
        b0 = fmaf(wa.y, bf_lo(u1.x), b0); b1 = fmaf(wa.y, bf_hi(u1.x), b1);
        b2 = fmaf(wa.y, bf_lo(u1.y), b2); b3 = fmaf(wa.y, bf_hi(u1.y), b3);
        a0 = fmaf(wa.z, bf_lo(u2.x), a0); a1 = fmaf(wa.z, bf_hi(u2.x), a1);
        a2 = fmaf(wa.z, bf_lo(u2.y), a2); a3 = fmaf(wa.z, bf_hi(u2.y), a3);
        b0 = fmaf(wa.w, bf_lo(u3.x), b0); b1 = fmaf(wa.w, bf_hi(u3.x), b1);
        b2 = fmaf(wa.w, bf_lo(u3.y), b2); b3 = fmaf(wa.w, bf_hi(u3.y), b3);
        a0 = fmaf(wb.x, bf_lo(u4.x), a0); a1 = fmaf(wb.x, bf_hi(u4.x), a1);
        a2 = fmaf(wb.x, bf_lo(u4.y), a2); a3 = fmaf(wb.x, bf_hi(u4.y), a3);
        b0 = fmaf(wb.y, bf_lo(u5.x), b0); b1 = fmaf(wb.y, bf_hi(u5.x), b1);
        b2 = fmaf(wb.y, bf_lo(u5.y), b2); b3 = fmaf(wb.y, bf_hi(u5.y), b3);
        a0 = fmaf(wb.z, bf_lo(u6.x), a0); a1 = fmaf(wb.z, bf_hi(u6.x), a1);
        a2 = fmaf(wb.z, bf_lo(u6.y), a2); a3 = fmaf(wb.z, bf_hi(u6.y), a3);
        b0 = fmaf(wb.w, bf_lo(u7.x), b0); b1 = fmaf(wb.w, bf_hi(u7.x), b1);
        b2 = fmaf(wb.w, bf_lo(u7.y), b2); b3 = fmaf(wb.w, bf_hi(u7.y), b3);
        s += ((wa.x + wa.y) + (wa.z + wa.w)) + ((wb.x + wb.y) + (wb.z + wb.w));
    }
    const float p0 = a0 + b0, p1 = a1 + b1, p2 = a2 + b2, p3 = a3 + b3;
    if (w) {
        float4 p; p.x = p0; p.y = p1; p.z = p2; p.w = p3;
        *(float4*)comb[w - 1][l] = p;
        if (l == 0) wspart[w] = s;
    } else if (l == 0) wspart[0] = s;
    __syncthreads();
    if (w == 0) {
        const float4 q0 = *(const float4*)comb[0][l];
        const float4 q1 = *(const float4*)comb[1][l];
        const float4 q2 = *(const float4*)comb[2][l];
        const float Z = (float)N_NODES + ((wspart[0] + wspart[1]) + (wspart[2] + wspart[3]));
        const float4 S4 = ((const float4*)S)[l];
        const float y0 = (S4.x + ((p0 + q0.x) + (q1.x + q2.x))) / Z;
        const float y1 = (S4.y + ((p1 + q0.y) + (q1.y + q2.y))) / Z;
        const float y2 = (S4.z + ((p2 + q0.z) + (q1.z + q2.z))) / Z;
        const float y3 = (S4.w + ((p3 + q0.w) + (q1.w + q2.w))) / Z;
        float4 o;
        o.x = y0 > 0.f ? y0 : expm1f(y0);
        o.y = y1 > 0.f ? y1 : expm1f(y1);
        o.z = y2 > 0.f ? y2 : expm1f(y2);
        o.w = y3 > 0.f ? y3 : expm1f(y3);
        ((float4*)(out + (size_t)r * OUT_F))[l] = o;
    }
}

// ---------------------------------------------------------------------------
extern "C" void kernel_launch(void* const* d_in, const int* in_sizes, int n_in,
                              void* d_out, int out_size, void* d_ws, size_t ws_size,
                              hipStream_t stream) {
    const float* feat = (const float*)d_in[0];
    const int*   eu   = (const int*)d_in[1];
    const int*   ev   = (const int*)d_in[2];
    const float* W    = (const float*)d_in[3];
    const float* blin = (const float*)d_in[4];
    const float* Was  = (const float*)d_in[5];
    const float* Wad  = (const float*)d_in[6];
    const float* batt = (const float*)d_in[7];
    float* out = (float*)d_out;

    // workspace layout (16B-aligned slices)
    char* p = (char*)d_ws;
    int4* slots = (int4*)p;                   p += (size_t)N_NODES * CAP * 16;    // 20.48 MB
    unsigned short* WhB = (unsigned short*)p; p += (size_t)N_NODES * OUT_F * 2;   // 5.12 MB
    unsigned short* WbfT = (unsigned short*)p; p += (size_t)IN_F * OUT_F * 2;     // 128 KB
    float* S    = (float*)p;                  p += OUT_F * 4;                     // 1 KB
    int*   cnt  = (int*)p;                    p += N_NODES * 4;                   // 40 KB (contiguous with S)
    float* dsv  = (float*)p;                  p += N_NODES * 4;
    float* ddv  = (float*)p;                  p += N_NODES * 4;

    hipMemsetAsync(S, 0, OUT_F * sizeof(float) + N_NODES * sizeof(int), stream);  // S + cnt

    wconv_kernel  <<<16,                    256, 0, stream>>>(W, WbfT);
    wh_kernel     <<<N_NODES / 16,          64,  0, stream>>>(feat, WbfT, blin, Was, Wad, WhB, dsv, ddv, S);
    scatter_kernel<<<(N_EDGES + 255) / 256, 256, 0, stream>>>(eu, ev, dsv, ddv, batt, cnt, slots);
    row_kernel    <<<N_NODES,               256, 0, stream>>>(WhB, S, cnt, slots, out);
}

// Round 10
// 184.791 us; speedup vs baseline: 2.1783x; 1.0902x over previous
//
#include <hip/hip_runtime.h>
#include <math.h>

#define N_NODES 10000
#define N_EDGES 320000
#define IN_F 256
#define OUT_F 256
#define SLOPE 0.2f
#define CAP 128   // per-row touch capacity; degree ~ Poisson(64), P(>128) < 1e-14

using f32x4 = __attribute__((ext_vector_type(4))) float;
using s16x8 = __attribute__((ext_vector_type(8))) short;
using u16x8 = __attribute__((ext_vector_type(8))) unsigned short;

__device__ __forceinline__ unsigned short f2bf_rtn(float x) {
    unsigned int u = __float_as_uint(x);
    u = (u + 0x7FFFu + ((u >> 16) & 1u)) >> 16;
    return (unsigned short)u;
}
__device__ __forceinline__ float bf_lo(unsigned int u) { return __uint_as_float(u << 16); }
__device__ __forceinline__ float bf_hi(unsigned int u) { return __uint_as_float(u & 0xFFFF0000u); }

// ---------------------------------------------------------------------------
// K0: W (K x N fp32, row-major) -> WbfT (N x K bf16, row-major) so MFMA
// B-fragments are contiguous 16B loads. 16 blocks x 64x64 tiles, LDS transpose.
// ---------------------------------------------------------------------------
__global__ __launch_bounds__(256) void wconv_kernel(const float* __restrict__ W,
                                                    unsigned short* __restrict__ WbfT) {
    __shared__ unsigned short t[64][72];   // +8 pad
    const int tid = threadIdx.x;
    const int k0 = (blockIdx.x >> 2) * 64, n0 = (blockIdx.x & 3) * 64;
#pragma unroll
    for (int i = 0; i < 16; ++i) {
        const int idx = i * 256 + tid;
        const int kk = idx >> 6, nn = idx & 63;
        t[nn][kk] = f2bf_rtn(W[(size_t)(k0 + kk) * 256 + n0 + nn]);
    }
    __syncthreads();
#pragma unroll
    for (int i = 0; i < 4; ++i) {
        const int q = i * 256 + tid;       // ushort4 id within tile
        const int nn = q >> 4, ch = q & 15;
        *(ushort4*)(WbfT + (size_t)(n0 + nn) * 256 + k0 + ch * 4) =
            *(const ushort4*)&t[nn][ch * 4];
    }
}

// ---------------------------------------------------------------------------
// K1: MFMA Wh GEMM (bf16 in, fp32 acc) + fused bf16 copy + ds/dd + colsum S.
// 625 blocks x 1 wave; wave owns 16 rows x 256 cols, K=256 (8 x 16 MFMAs).
// C/D layout (verified m89): col = lane&15, row = (lane>>4)*4 + reg.
// ---------------------------------------------------------------------------
__global__ __launch_bounds__(64, 1) void wh_kernel(
    const float* __restrict__ feat, const unsigned short* __restrict__ WbfT,
    const float* __restrict__ b, const float* __restrict__ Was,
    const float* __restrict__ Wad, unsigned short* __restrict__ WhB,
    float* __restrict__ ds, float* __restrict__ dd, float* __restrict__ S)
{
    __shared__ unsigned short lt[16][264];   // 16x256 bf16 tile, +8 pad
    const int l = threadIdx.x;
    const int c = l & 15, h = l >> 4;
    const int rbase = blockIdx.x * 16;

    float wasv[16], wadv[16];
    f32x4 acc[16];
#pragma unroll
    for (int nt = 0; nt < 16; ++nt) {
        wasv[nt] = Was[nt * 16 + c];
        wadv[nt] = Wad[nt * 16 + c];
        const float bv = b[nt * 16 + c];
        acc[nt] = (f32x4){bv, bv, bv, bv};   // bias as C-in (col = lane&15)
    }

    const float* arow = feat + (size_t)(rbase + c) * IN_F + h * 8;
    const unsigned short* bbase = WbfT + (size_t)c * 256 + h * 8;
#pragma unroll
    for (int kt = 0; kt < 8; ++kt) {
        const float4 f0 = *(const float4*)(arow + kt * 32);
        const float4 f1 = *(const float4*)(arow + kt * 32 + 4);
        s16x8 a;
        a[0] = (short)f2bf_rtn(f0.x); a[1] = (short)f2bf_rtn(f0.y);
        a[2] = (short)f2bf_rtn(f0.z); a[3] = (short)f2bf_rtn(f0.w);
        a[4] = (short)f2bf_rtn(f1.x); a[5] = (short)f2bf_rtn(f1.y);
        a[6] = (short)f2bf_rtn(f1.z); a[7] = (short)f2bf_rtn(f1.w);
        s16x8 bb[16];
#pragma unroll
        for (int nt = 0; nt < 16; ++nt)      // 16 independent 16B L2 loads in flight
            bb[nt] = *(const s16x8*)(bbase + (size_t)nt * 16 * 256 + kt * 32);
#pragma unroll
        for (int nt = 0; nt < 16; ++nt)
            acc[nt] = __builtin_amdgcn_mfma_f32_16x16x32_bf16(a, bb[nt], acc[nt], 0, 0, 0);
    }

    // ds/dd: lane partial over its 16 cols, reduce across lane&15 group
    float pds[4] = {0.f, 0.f, 0.f, 0.f}, pdd[4] = {0.f, 0.f, 0.f, 0.f};
#pragma unroll
    for (int nt = 0; nt < 16; ++nt)
#pragma unroll
        for (int r = 0; r < 4; ++r) {
            pds[r] = fmaf(acc[nt][r], wasv[nt], pds[r]);
            pdd[r] = fmaf(acc[nt][r], wadv[nt], pdd[r]);
        }
#pragma unroll
    for (int r = 0; r < 4; ++r) {
#pragma unroll
        for (int m = 1; m < 16; m <<= 1) {
            pds[r] += __shfl_xor(pds[r], m);
            pdd[r] += __shfl_xor(pdd[r], m);
        }
    }
    if (c == 0) {
#pragma unroll
        for (int r = 0; r < 4; ++r) {
            ds[rbase + h * 4 + r] = pds[r];
            dd[rbase + h * 4 + r] = pdd[r];
        }
    }

    // column sums -> S
#pragma unroll
    for (int nt = 0; nt < 16; ++nt) {
        float v = (acc[nt][0] + acc[nt][1]) + (acc[nt][2] + acc[nt][3]);
        v += __shfl_xor(v, 16);
        v += __shfl_xor(v, 32);
        if (h == 0) atomicAdd(&S[nt * 16 + c], v);
    }

    // WhB: bf16 tile via LDS transpose -> coalesced ushort8 stores
#pragma unroll
    for (int nt = 0; nt < 16; ++nt)
#pragma unroll
        for (int r = 0; r < 4; ++r)
            lt[h * 4 + r][nt * 16 + c] = f2bf_rtn(acc[nt][r]);
    __syncthreads();
#pragma unroll
    for (int i = 0; i < 8; ++i) {
        const int g = i * 64 + l;            // ushort8 chunk id (512 total)
        const int row = g >> 5, ch = g & 31;
        ((u16x8*)(WhB + (size_t)rbase * 256))[g] = *(const u16x8*)&lt[row][ch * 8];
    }
}

// ---------------------------------------------------------------------------
// K2: scatter (col, phase) into fixed-CAP row buckets — 4B entries, no e.
// Per cell (r,c) only TWO e values exist (phase1: ds[r]+dd[c]+b from edge
// (r,c); phase2: ds[c]+dd[r]+b from edge (c,r)); jnp last-write-wins ==
// "phase2 beats phase1; same-phase dups keep one". So a 1-bit phase replaces
// the order tag, and e is recomputed bit-exactly in K3.
// ---------------------------------------------------------------------------
__global__ void scatter_kernel(const int* __restrict__ eu, const int* __restrict__ ev,
                               int* __restrict__ cnt, int* __restrict__ slots) {
    const int i = blockIdx.x * blockDim.x + threadIdx.x;
    if (i >= N_EDGES) return;
    const int u = eu[i], v = ev[i];
    const int p = atomicAdd(&cnt[u], 1);
    if (p < CAP) slots[u * CAP + p] = (v << 1);        // phase1: cell (u,v)
    const int q = atomicAdd(&cnt[v], 1);
    if (q < CAP) slots[v * CAP + q] = (u << 1) | 1;    // phase2: cell (v,u)
}

// ---------------------------------------------------------------------------
// K3: per-row e-recompute + dedupe + softmax-weighted gather + ELU.
// Staging: e = gd[ph*N+c] + (ph ? ddr : dsr) + b  (gd = [dd | ds] combined,
// fp32, bit-identical to the reference's ds[u]+dd[v]+b). Dedupe key
// q=(col<<8)|(ph<<7)|(127-slot): winner per col = max q.
// One block (256 thr = 4 waves) per row; wave covers the full 256-feature row
// via uint2 per lane; wave w owns touch quarter w; LDS combine.
// ---------------------------------------------------------------------------
__global__ __launch_bounds__(256) void row_kernel(
    const unsigned short* __restrict__ WhB, const float* __restrict__ S,
    const int* __restrict__ cnt, const int* __restrict__ slots,
    const float* __restrict__ gd,   // gd[0..N) = dd, gd[N..2N) = ds
    const float* __restrict__ batt, float* __restrict__ out)
{
    __shared__ __attribute__((aligned(16))) float sw[CAP];
    __shared__ __attribute__((aligned(16))) int   scol[CAP];
    __shared__ __attribute__((aligned(16))) int   sq[CAP + 4];
    __shared__ float comb[3][64][4];
    __shared__ float wspart[4];
    const int r   = blockIdx.x;
    const int tid = threadIdx.x;
    const int w   = tid >> 6;             // wave -> touch quarter
    const int l   = tid & 63;             // lane -> 4 features
    int k = cnt[r];
    if (k > CAP) k = CAP;
    const float ddr = gd[r], dsr = gd[N_NODES + r], bA = batt[0];
    if (tid < CAP) {
        if (tid < k) {
            const int s = slots[(size_t)r * CAP + tid];
            const int c = s >> 1, ph = s & 1;
            scol[tid] = c;
            sq[tid]   = (c << 8) | (ph << 7) | (127 - tid);
            const float e = (gd[ph * N_NODES + c] + (ph ? ddr : dsr)) + bA;
            const float lr = e >= 0.f ? e : SLOPE * e;
            sw[tid] = __expf(lr) - 1.f;
        } else { scol[tid] = 0; sq[tid] = 1 << 30; sw[tid] = 0.f; }  // pad col never matches
    } else if (tid < CAP + 4) {
        sq[tid] = 1 << 30;
    }
    __syncthreads();
    // dedupe: zero every touch that is not the max-q of its column
    if (tid < k) {
        const int qj = sq[tid], cj = qj >> 8;
        const int4* q4 = (const int4*)sq;
        const int kk4 = (k + 3) >> 2;
        bool dup = false;
        for (int t = 0; t < kk4; ++t) {
            const int4 qq = q4[t];
            dup = dup | ((qq.x >> 8) == cj && qq.x > qj)
                      | ((qq.y >> 8) == cj && qq.y > qj)
                      | ((qq.z >> 8) == cj && qq.z > qj)
                      | ((qq.w >> 8) == cj && qq.w > qj);
        }
        if (dup) sw[tid] = 0.f;
    }
    __syncthreads();

    const int k32 = (k + 31) & ~31;
    const int kq  = k32 >> 2;             // per-wave touches, multiple of 8
    const int j0  = w * kq;
    const uint2* wp = (const uint2*)WhB + l;   // row stride = 64 uint2
    float a0 = 0.f, a1 = 0.f, a2 = 0.f, a3 = 0.f;
    float b0 = 0.f, b1 = 0.f, b2 = 0.f, b3 = 0.f;
    float s = 0.f;
    for (int j = j0; j < j0 + kq; j += 8) {
        const float4 wa = *(const float4*)&sw[j];      // LDS b128 broadcast
        const float4 wb = *(const float4*)&sw[j + 4];
        const int4   ca = *(const int4*)&scol[j];
        const int4   cb = *(const int4*)&scol[j + 4];
        const uint2 u0 = wp[(size_t)ca.x << 6];        // 8 independent 8B gathers
        const uint2 u1 = wp[(size_t)ca.y << 6];
        const uint2 u2 = wp[(size_t)ca.z << 6];
        const uint2 u3 = wp[(size_t)ca.w << 6];
        const uint2 u4 = wp[(size_t)cb.x << 6];
        const uint2 u5 = wp[(size_t)cb.y << 6];
        const uint2 u6 = wp[(size_t)cb.z << 6];
        const uint2 u7 = wp[(size_t)cb.w << 6];
        a0 = fmaf(wa.x, bf_lo(u0.x), a0); a1 = fmaf(wa.x, bf_hi(u0.x), a1);
        a2 = fmaf(wa.x, bf_lo(u0.y), a2); a3 = fmaf(wa.x, bf_hi(u0.y), a3);
        b0 = fmaf(wa.y, bf_lo(u1.x), b0); b1 = fmaf(wa.y, bf_hi(u1.x), b1);
        b2 = fmaf(wa.y, bf_lo(u1.y), b2); b3 = fmaf(wa.y, bf_hi(u1.y), b3);
        a0 = fmaf(wa.z, bf_lo(u2.x), a0); a1 = fmaf(wa.z, bf_hi(u2.x), a1);
        a2 = fmaf(wa.z, bf_lo(u2.y), a2); a3 = fmaf(wa.z, bf_hi(u2.y), a3);
        b0 = fmaf(wa.w, bf_lo(u3.x), b0); b1 = fmaf(wa.w, bf_hi(u3.x), b1);
        b2 = fmaf(wa.w, bf_lo(u3.y), b2); b3 = fmaf(wa.w, bf_hi(u3.y), b3);
        a0 = fmaf(wb.x, bf_lo(u4.x), a0); a1 = fmaf(wb.x, bf_hi(u4.x), a1);
        a2 = fmaf(wb.x, bf_lo(u4.y), a2); a3 = fmaf(wb.x, bf_hi(u4.y), a3);
        b0 = fmaf(wb.y, bf_lo(u5.x), b0); b1 = fmaf(wb.y, bf_hi(u5.x), b1);
        b2 = fmaf(wb.y, bf_lo(u5.y), b2); b3 = fmaf(wb.y, bf_hi(u5.y), b3);
        a0 = fmaf(wb.z, bf_lo(u6.x), a0); a1 = fmaf(wb.z, bf_hi(u6.x), a1);
        a2 = fmaf(wb.z, bf_lo(u6.y), a2); a3 = fmaf(wb.z, bf_hi(u6.y), a3);
        b0 = fmaf(wb.w, bf_lo(u7.x), b0); b1 = fmaf(wb.w, bf_hi(u7.x), b1);
        b2 = fmaf(wb.w, bf_lo(u7.y), b2); b3 = fmaf(wb.w, bf_hi(u7.y), b3);
        s += ((wa.x + wa.y) + (wa.z + wa.w)) + ((wb.x + wb.y) + (wb.z + wb.w));
    }
    const float p0 = a0 + b0, p1 = a1 + b1, p2 = a2 + b2, p3 = a3 + b3;
    if (w) {
        float4 p; p.x = p0; p.y = p1; p.z = p2; p.w = p3;
        *(float4*)comb[w - 1][l] = p;
        if (l == 0) wspart[w] = s;
    } else if (l == 0) wspart[0] = s;
    __syncthreads();
    if (w == 0) {
        const float4 q0 = *(const float4*)comb[0][l];
        const float4 q1 = *(const float4*)comb[1][l];
        const float4 q2 = *(const float4*)comb[2][l];
        const float Z = (float)N_NODES + ((wspart[0] + wspart[1]) + (wspart[2] + wspart[3]));
        const float4 S4 = ((const float4*)S)[l];
        const float y0 = (S4.x + ((p0 + q0.x) + (q1.x + q2.x))) / Z;
        const float y1 = (S4.y + ((p1 + q0.y) + (q1.y + q2.y))) / Z;
        const float y2 = (S4.z + ((p2 + q0.z) + (q1.z + q2.z))) / Z;
        const float y3 = (S4.w + ((p3 + q0.w) + (q1.w + q2.w))) / Z;
        float4 o;
        o.x = y0 > 0.f ? y0 : expm1f(y0);
        o.y = y1 > 0.f ? y1 : expm1f(y1);
        o.z = y2 > 0.f ? y2 : expm1f(y2);
        o.w = y3 > 0.f ? y3 : expm1f(y3);
        ((float4*)(out + (size_t)r * OUT_F))[l] = o;
    }
}

// ---------------------------------------------------------------------------
extern "C" void kernel_launch(void* const* d_in, const int* in_sizes, int n_in,
                              void* d_out, int out_size, void* d_ws, size_t ws_size,
                              hipStream_t stream) {
    const float* feat = (const float*)d_in[0];
    const int*   eu   = (const int*)d_in[1];
    const int*   ev   = (const int*)d_in[2];
    const float* W    = (const float*)d_in[3];
    const float* blin = (const float*)d_in[4];
    const float* Was  = (const float*)d_in[5];
    const float* Wad  = (const float*)d_in[6];
    const float* batt = (const float*)d_in[7];
    float* out = (float*)d_out;

    // workspace layout (16B-aligned slices)
    char* p = (char*)d_ws;
    int* slots = (int*)p;                     p += (size_t)N_NODES * CAP * 4;     // 5.12 MB
    unsigned short* WhB = (unsigned short*)p; p += (size_t)N_NODES * OUT_F * 2;   // 5.12 MB
    unsigned short* WbfT = (unsigned short*)p; p += (size_t)IN_F * OUT_F * 2;     // 128 KB
    float* S    = (float*)p;                  p += OUT_F * 4;                     // 1 KB
    int*   cnt  = (int*)p;                    p += N_NODES * 4;                   // 40 KB (contiguous with S)
    float* gd   = (float*)p;                  p += 2 * N_NODES * 4;               // [dd | ds]
    float* ddv  = gd;
    float* dsv  = gd + N_NODES;

    hipMemsetAsync(S, 0, OUT_F * sizeof(float) + N_NODES * sizeof(int), stream);  // S + cnt

    wconv_kernel  <<<16,                    256, 0, stream>>>(W, WbfT);
    wh_kernel     <<<N_NODES / 16,          64,  0, stream>>>(feat, WbfT, blin, Was, Wad, WhB, dsv, ddv, S);
    scatter_kernel<<<(N_EDGES + 255) / 256, 256, 0, stream>>>(eu, ev, cnt, slots);
    row_kernel    <<<N_NODES,               256, 0, stream>>>(WhB, S, cnt, slots, gd, batt, out);
}

// Round 12
// 181.057 us; speedup vs baseline: 2.2233x; 1.0206x over previous
//
#include <hip/hip_runtime.h>
#include <math.h>

#define N_NODES 10000
#define N_EDGES 320000
#define IN_F 256
#define OUT_F 256
#define SLOPE 0.2f
#define CAP 128   // per-row touch capacity; degree ~ Poisson(64), P(>128) < 1e-14

using f32x4 = __attribute__((ext_vector_type(4))) float;
using s16x8 = __attribute__((ext_vector_type(8))) short;
using u16x8 = __attribute__((ext_vector_type(8))) unsigned short;

__device__ __forceinline__ unsigned short f2bf_rtn(float x) {
    unsigned int u = __float_as_uint(x);
    u = (u + 0x7FFFu + ((u >> 16) & 1u)) >> 16;
    return (unsigned short)u;
}
__device__ __forceinline__ float bf_lo(unsigned int u) { return __uint_as_float(u << 16); }
__device__ __forceinline__ float bf_hi(unsigned int u) { return __uint_as_float(u & 0xFFFF0000u); }

// ---------------------------------------------------------------------------
// K0: W (K x N fp32, row-major) -> WbfT (N x K bf16, row-major) so MFMA
// B-fragments are contiguous 16B loads. 16 blocks x 64x64 tiles, LDS transpose.
// ---------------------------------------------------------------------------
__global__ __launch_bounds__(256) void wconv_kernel(const float* __restrict__ W,
                                                    unsigned short* __restrict__ WbfT) {
    __shared__ unsigned short t[64][72];   // +8 pad
    const int tid = threadIdx.x;
    const int k0 = (blockIdx.x >> 2) * 64, n0 = (blockIdx.x & 3) * 64;
#pragma unroll
    for (int i = 0; i < 16; ++i) {
        const int idx = i * 256 + tid;
        const int kk = idx >> 6, nn = idx & 63;
        t[nn][kk] = f2bf_rtn(W[(size_t)(k0 + kk) * 256 + n0 + nn]);
    }
    __syncthreads();
#pragma unroll
    for (int i = 0; i < 4; ++i) {
        const int q = i * 256 + tid;       // ushort4 id within tile
        const int nn = q >> 4, ch = q & 15;
        *(ushort4*)(WbfT + (size_t)(n0 + nn) * 256 + k0 + ch * 4) =
            *(const ushort4*)&t[nn][ch * 4];
    }
}

// ---------------------------------------------------------------------------
// K1: MFMA Wh GEMM + fused bf16 copy + ds/dd + colsum S.
// 625 blocks x 8 WAVES (512 thr); wave w owns 16 rows x 32 cols (nt = 2)
// -> 5000 waves ~ 4.9/SIMD (was 625 waves = 0.6/SIMD, L2-latency exposed).
// feat staged once per block in LDS as bf16 (A-frags = ds_read_b128);
// W L2 traffic unchanged (col-split doesn't duplicate W).
// C/D layout (verified m89): col = lane&15, row = (lane>>4)*4 + reg.
// ---------------------------------------------------------------------------
__global__ __launch_bounds__(512) void wh_kernel(
    const float* __restrict__ feat, const unsigned short* __restrict__ WbfT,
    const float* __restrict__ b, const float* __restrict__ Was,
    const float* __restrict__ Wad, unsigned short* __restrict__ WhB,
    float* __restrict__ ds, float* __restrict__ dd, float* __restrict__ S)
{
    __shared__ unsigned short sfb[16][264];  // bf16 feat tile (reused as Wh tile), +8 pad
    __shared__ float dsred[8][16];
    __shared__ float ddred[8][16];
    const int tid = threadIdx.x;
    const int l = tid & 63, w = tid >> 6;    // 8 waves
    const int c = l & 15, h = l >> 4;
    const int rbase = blockIdx.x * 16;
    const int col0 = w * 32;                 // wave's 32-col slice

    {   // stage feat 16x256 fp32 -> bf16 LDS (2 float4 per thread, RTN)
        const float4* src = (const float4*)(feat + (size_t)rbase * IN_F);
        for (int i = tid; i < 1024; i += 512) {
            const float4 f = src[i];
            ushort4 pk;
            pk.x = f2bf_rtn(f.x); pk.y = f2bf_rtn(f.y);
            pk.z = f2bf_rtn(f.z); pk.w = f2bf_rtn(f.w);
            *(ushort4*)&sfb[i >> 6][(i & 63) * 4] = pk;
        }
    }
    __syncthreads();

    float wasv[2], wadv[2];
    f32x4 acc[2];
#pragma unroll
    for (int nt = 0; nt < 2; ++nt) {
        const int gc = col0 + nt * 16 + c;
        wasv[nt] = Was[gc]; wadv[nt] = Wad[gc];
        const float bv = b[gc];
        acc[nt] = (f32x4){bv, bv, bv, bv};   // bias as C-in (col = lane&15)
    }

    const unsigned short* bbase = WbfT + (size_t)(col0 + c) * 256 + h * 8;
#pragma unroll
    for (int kt = 0; kt < 8; ++kt) {
        const s16x8 a  = *(const s16x8*)&sfb[c][kt * 32 + h * 8];  // LDS b128
        const s16x8 b0 = *(const s16x8*)(bbase + kt * 32);         // L2 16B
        const s16x8 b1 = *(const s16x8*)(bbase + 16 * 256 + kt * 32);
        acc[0] = __builtin_amdgcn_mfma_f32_16x16x32_bf16(a, b0, acc[0], 0, 0, 0);
        acc[1] = __builtin_amdgcn_mfma_f32_16x16x32_bf16(a, b1, acc[1], 0, 0, 0);
    }

    // ds/dd partials over this wave's 32 cols; reduce across the 16-lane c group
    float pds[4], pdd[4];
#pragma unroll
    for (int r = 0; r < 4; ++r) {
        pds[r] = acc[0][r] * wasv[0] + acc[1][r] * wasv[1];
        pdd[r] = acc[0][r] * wadv[0] + acc[1][r] * wadv[1];
    }
#pragma unroll
    for (int r = 0; r < 4; ++r) {
#pragma unroll
        for (int m = 1; m < 16; m <<= 1) {
            pds[r] += __shfl_xor(pds[r], m);
            pdd[r] += __shfl_xor(pdd[r], m);
        }
    }
    if (c == 0) {
#pragma unroll
        for (int r = 0; r < 4; ++r) {
            dsred[w][h * 4 + r] = pds[r];
            ddred[w][h * 4 + r] = pdd[r];
        }
    }

    // column sums -> S (each wave owns distinct cols; reduce over h groups)
#pragma unroll
    for (int nt = 0; nt < 2; ++nt) {
        float v = (acc[nt][0] + acc[nt][1]) + (acc[nt][2] + acc[nt][3]);
        v += __shfl_xor(v, 16);
        v += __shfl_xor(v, 32);
        if (h == 0) atomicAdd(&S[col0 + nt * 16 + c], v);
    }
    __syncthreads();                         // dsred ready; feat reads done

    if (tid < 16) {
        float s1 = 0.f, s2 = 0.f;
#pragma unroll
        for (int ww = 0; ww < 8; ++ww) { s1 += dsred[ww][tid]; s2 += ddred[ww][tid]; }
        ds[rbase + tid] = s1;
        dd[rbase + tid] = s2;
    }

    // Wh bf16 tile: overwrite sfb (feat no longer needed), then coalesced store
#pragma unroll
    for (int nt = 0; nt < 2; ++nt)
#pragma unroll
        for (int r = 0; r < 4; ++r)
            sfb[h * 4 + r][col0 + nt * 16 + c] = f2bf_rtn(acc[nt][r]);
    __syncthreads();
    {   // 512 u16x8 chunks, one per thread
        const int row = tid >> 5, ch = tid & 31;
        *(u16x8*)(WhB + (size_t)(rbase + row) * 256 + ch * 8) = *(const u16x8*)&sfb[row][ch * 8];
    }
}

// ---------------------------------------------------------------------------
// K2: scatter (col, phase) into fixed-CAP row buckets — 4B entries, no e.
// Per cell (r,c) only TWO e values exist (phase1: ds[r]+dd[c]+b from edge
// (r,c); phase2: ds[c]+dd[r]+b from edge (c,r)); jnp last-write-wins ==
// "phase2 beats phase1; same-phase dups keep one". So a 1-bit phase replaces
// the order tag, and e is recomputed bit-exactly in K3.
// ---------------------------------------------------------------------------
__global__ void scatter_kernel(const int* __restrict__ eu, const int* __restrict__ ev,
                               int* __restrict__ cnt, int* __restrict__ slots) {
    const int i = blockIdx.x * blockDim.x + threadIdx.x;
    if (i >= N_EDGES) return;
    const int u = eu[i], v = ev[i];
    const int p = atomicAdd(&cnt[u], 1);
    if (p < CAP) slots[u * CAP + p] = (v << 1);        // phase1: cell (u,v)
    const int q = atomicAdd(&cnt[v], 1);
    if (q < CAP) slots[v * CAP + q] = (u << 1) | 1;    // phase2: cell (v,u)
}

// ---------------------------------------------------------------------------
// K3: per-row e-recompute + dedupe + softmax-weighted gather + ELU.
// Staging: e = gd[ph*N+c] + (ph ? ddr : dsr) + b  (gd = [dd | ds] combined,
// fp32, bit-identical to the reference's ds[u]+dd[v]+b). Dedupe key
// q=(col<<8)|(ph<<7)|(127-slot): winner per col = max q.
// One block (256 thr = 4 waves) per row; wave covers the full 256-feature row
// via uint2 per lane; wave w owns touch quarter w; LDS combine.
// ---------------------------------------------------------------------------
__global__ __launch_bounds__(256) void row_kernel(
    const unsigned short* __restrict__ WhB, const float* __restrict__ S,
    const int* __restrict__ cnt, const int* __restrict__ slots,
    const float* __restrict__ gd,   // gd[0..N) = dd, gd[N..2N) = ds
    const float* __restrict__ batt, float* __restrict__ out)
{
    __shared__ __attribute__((aligned(16))) float sw[CAP];
    __shared__ __attribute__((aligned(16))) int   scol[CAP];
    __shared__ __attribute__((aligned(16))) int   sq[CAP + 4];
    __shared__ float comb[3][64][4];
    __shared__ float wspart[4];
    const int r   = blockIdx.x;
    const int tid = threadIdx.x;
    const int w   = tid >> 6;             // wave -> touch quarter
    const int l   = tid & 63;             // lane -> 4 features
    int k = cnt[r];
    if (k > CAP) k = CAP;
    const float ddr = gd[r], dsr = gd[N_NODES + r], bA = batt[0];
    if (tid < CAP) {
        if (tid < k) {
            const int s = slots[(size_t)r * CAP + tid];
            const int c = s >> 1, ph = s & 1;
            scol[tid] = c;
            sq[tid]   = (c << 8) | (ph << 7) | (127 - tid);
            const float e = (gd[ph * N_NODES + c] + (ph ? ddr : dsr)) + bA;
            const float lr = e >= 0.f ? e : SLOPE * e;
            sw[tid] = __expf(lr) - 1.f;
        } else { scol[tid] = 0; sq[tid] = 1 << 30; sw[tid] = 0.f; }  // pad col never matches
    } else if (tid < CAP + 4) {
        sq[tid] = 1 << 30;
    }
    __syncthreads();
    // dedupe: zero every touch that is not the max-q of its column
    if (tid < k) {
        const int qj = sq[tid], cj = qj >> 8;
        const int4* q4 = (const int4*)sq;
        const int kk4 = (k + 3) >> 2;
        bool dup = false;
        for (int t = 0; t < kk4; ++t) {
            const int4 qq = q4[t];
            dup = dup | ((qq.x >> 8) == cj && qq.x > qj)
                      | ((qq.y >> 8) == cj && qq.y > qj)
                      | ((qq.z >> 8) == cj && qq.z > qj)
                      | ((qq.w >> 8) == cj && qq.w > qj);
        }
        if (dup) sw[tid] = 0.f;
    }
    __syncthreads();

    const int k32 = (k + 31) & ~31;
    const int kq  = k32 >> 2;             // per-wave touches, multiple of 8
    const int j0  = w * kq;
    const uint2* wp = (const uint2*)WhB + l;   // row stride = 64 uint2
    float a0 = 0.f, a1 = 0.f, a2 = 0.f, a3 = 0.f;
    float b0 = 0.f, b1 = 0.f, b2 = 0.f, b3 = 0.f;
    float s = 0.f;
    for (int j = j0; j < j0 + kq; j += 8) {
        const float4 wa = *(const float4*)&sw[j];      // LDS b128 broadcast
        const float4 wb = *(const float4*)&sw[j + 4];
        const int4   ca = *(const int4*)&scol[j];
        const int4   cb = *(const int4*)&scol[j + 4];
        const uint2 u0 = wp[(size_t)ca.x << 6];        // 8 independent 8B gathers
        const uint2 u1 = wp[(size_t)ca.y << 6];
        const uint2 u2 = wp[(size_t)ca.z << 6];
        const uint2 u3 = wp[(size_t)ca.w << 6];
        const uint2 u4 = wp[(size_t)cb.x << 6];
        const uint2 u5 = wp[(size_t)cb.y << 6];
        const uint2 u6 = wp[(size_t)cb.z << 6];
        const uint2 u7 = wp[(size_t)cb.w << 6];
        a0 = fmaf(wa.x, bf_lo(u0.x), a0); a1 = fmaf(wa.x, bf_hi(u0.x), a1);
        a2 = fmaf(wa.x, bf_lo(u0.y), a2); a3 = fmaf(wa.x, bf_hi(u0.y), a3);
        b0 = fmaf(wa.y, bf_lo(u1.x), b0); b1 = fmaf(wa.y, bf_hi(u1.x), b1);
        b2 = fmaf(wa.y, bf_lo(u1.y), b2); b3 = fmaf(wa.y, bf_hi(u1.y), b3);
        a0 = fmaf(wa.z, bf_lo(u2.x), a0); a1 = fmaf(wa.z, bf_hi(u2.x), a1);
        a2 = fmaf(wa.z, bf_lo(u2.y), a2); a3 = fmaf(wa.z, bf_hi(u2.y), a3);
        b0 = fmaf(wa.w, bf_lo(u3.x), b0); b1 = fmaf(wa.w, bf_hi(u3.x), b1);
        b2 = fmaf(wa.w, bf_lo(u3.y), b2); b3 = fmaf(wa.w, bf_hi(u3.y), b3);
        a0 = fmaf(wb.x, bf_lo(u4.x), a0); a1 = fmaf(wb.x, bf_hi(u4.x), a1);
        a2 = fmaf(wb.x, bf_lo(u4.y), a2); a3 = fmaf(wb.x, bf_hi(u4.y), a3);
        b0 = fmaf(wb.y, bf_lo(u5.x), b0); b1 = fmaf(wb.y, bf_hi(u5.x), b1);
        b2 = fmaf(wb.y, bf_lo(u5.y), b2); b3 = fmaf(wb.y, bf_hi(u5.y), b3);
        a0 = fmaf(wb.z, bf_lo(u6.x), a0); a1 = fmaf(wb.z, bf_hi(u6.x), a1);
        a2 = fmaf(wb.z, bf_lo(u6.y), a2); a3 = fmaf(wb.z, bf_hi(u6.y), a3);
        b0 = fmaf(wb.w, bf_lo(u7.x), b0); b1 = fmaf(wb.w, bf_hi(u7.x), b1);
        b2 = fmaf(wb.w, bf_lo(u7.y), b2); b3 = fmaf(wb.w, bf_hi(u7.y), b3);
        s += ((wa.x + wa.y) + (wa.z + wa.w)) + ((wb.x + wb.y) + (wb.z + wb.w));
    }
    const float p0 = a0 + b0, p1 = a1 + b1, p2 = a2 + b2, p3 = a3 + b3;
    if (w) {
        float4 p; p.x = p0; p.y = p1; p.z = p2; p.w = p3;
        *(float4*)comb[w - 1][l] = p;
        if (l == 0) wspart[w] = s;
    } else if (l == 0) wspart[0] = s;
    __syncthreads();
    if (w == 0) {
        const float4 q0 = *(const float4*)comb[0][l];
        const float4 q1 = *(const float4*)comb[1][l];
        const float4 q2 = *(const float4*)comb[2][l];
        const float Z = (float)N_NODES + ((wspart[0] + wspart[1]) + (wspart[2] + wspart[3]));
        const float4 S4 = ((const float4*)S)[l];
        const float y0 = (S4.x + ((p0 + q0.x) + (q1.x + q2.x))) / Z;
        const float y1 = (S4.y + ((p1 + q0.y) + (q1.y + q2.y))) / Z;
        const float y2 = (S4.z + ((p2 + q0.z) + (q1.z + q2.z))) / Z;
        const float y3 = (S4.w + ((p3 + q0.w) + (q1.w + q2.w))) / Z;
        float4 o;
        o.x = y0 > 0.f ? y0 : expm1f(y0);
        o.y = y1 > 0.f ? y1 : expm1f(y1);
        o.z = y2 > 0.f ? y2 : expm1f(y2);
        o.w = y3 > 0.f ? y3 : expm1f(y3);
        ((float4*)(out + (size_t)r * OUT_F))[l] = o;
    }
}

// ---------------------------------------------------------------------------
extern "C" void kernel_launch(void* const* d_in, const int* in_sizes, int n_in,
                              void* d_out, int out_size, void* d_ws, size_t ws_size,
                              hipStream_t stream) {
    const float* feat = (const float*)d_in[0];
    const int*   eu   = (const int*)d_in[1];
    const int*   ev   = (const int*)d_in[2];
    const float* W    = (const float*)d_in[3];
    const float* blin = (const float*)d_in[4];
    const float* Was  = (const float*)d_in[5];
    const float* Wad  = (const float*)d_in[6];
    const float* batt = (const float*)d_in[7];
    float* out = (float*)d_out;

    // workspace layout (16B-aligned slices)
    char* p = (char*)d_ws;
    int* slots = (int*)p;                     p += (size_t)N_NODES * CAP * 4;     // 5.12 MB
    unsigned short* WhB = (unsigned short*)p; p += (size_t)N_NODES * OUT_F * 2;   // 5.12 MB
    unsigned short* WbfT = (unsigned short*)p; p += (size_t)IN_F * OUT_F * 2;     // 128 KB
    float* S    = (float*)p;                  p += OUT_F * 4;                     // 1 KB
    int*   cnt  = (int*)p;                    p += N_NODES * 4;                   // 40 KB (contiguous with S)
    float* gd   = (float*)p;                  p += 2 * N_NODES * 4;               // [dd | ds]
    float* ddv  = gd;
    float* dsv  = gd + N_NODES;

    hipMemsetAsync(S, 0, OUT_F * sizeof(float) + N_NODES * sizeof(int), stream);  // S + cnt

    wconv_kernel  <<<16,                    256, 0, stream>>>(W, WbfT);
    wh_kernel     <<<N_NODES / 16,          512, 0, stream>>>(feat, WbfT, blin, Was, Wad, WhB, dsv, ddv, S);
    scatter_kernel<<<(N_EDGES + 255) / 256, 256, 0, stream>>>(eu, ev, cnt, slots);
    row_kernel    <<<N_NODES,               256, 0, stream>>>(WhB, S, cnt, slots, gd, batt, out);
}